// Round 8
// baseline (1608.729 us; speedup 1.0000x reference)
//
#include <hip/hip_runtime.h>
#include <math.h>

#define FMC   512
#define DIMX  1024
#define NCC   157
#define NTOK  10
#define NHEAD 4
#define BBATCH 8
#define TTIME 4096
#define NLAYERS 5
#define NSEG  64
#define WROWS 1664   // 3*512 dal qkv + 40 qkh + 88 zero pad

typedef short bf16x8 __attribute__((ext_vector_type(8)));
typedef float f32x4v __attribute__((ext_vector_type(4)));
typedef unsigned short u16x8 __attribute__((ext_vector_type(8)));
typedef unsigned short u16x4 __attribute__((ext_vector_type(4)));

__device__ __forceinline__ float b2f(unsigned short u){
    union { unsigned int i; float f; } v; v.i = ((unsigned int)u) << 16; return v.f;
}
__device__ __forceinline__ unsigned short f2b(float f){
    union { float f; unsigned int i; } v; v.f = f;
    unsigned int r = v.i + 0x7FFFu + ((v.i >> 16) & 1u);
    return (unsigned short)(r >> 16);
}

struct Outs3 { unsigned short* p[3]; };

// lgkm drain + raw barrier (NO vmcnt drain — global prefetch stays in flight).
// sched_barrier fences per guide rule #18.
#define LDS_BARRIER() do { \
    __builtin_amdgcn_sched_barrier(0); \
    asm volatile("s_waitcnt lgkmcnt(0)" ::: "memory"); \
    __builtin_amdgcn_s_barrier(); \
    __builtin_amdgcn_sched_barrier(0); \
} while (0)

// ---------------------------------------------------------------------------
// MFMA GEMM: C[b,t,m] = sum_k W[m,k] * X[b,t,k]   (bf16 in, fp32 acc)
// Block 128m x 128t, BK=64, 4 waves (2x2). Depth-2 reg-staged pipeline with
// RAW barriers: tile for step k is loaded at step k-2, so the compiler's
// auto-inserted vmcnt before the LDS write is COUNTED (8 newer loads in
// flight), and no barrier ever drains vmcnt to 0 mid-loop (T4).
// ---------------------------------------------------------------------------
template<int KSTEPS,int HAS_BIAS,int HAS_RESID,int HAS_MASK,int SPLIT,int CMAJOR>
__global__ __launch_bounds__(256) void gemm_mfma(
    const unsigned short* __restrict__ W, const unsigned short* __restrict__ X,
    int M,
    const float* __restrict__ bias, const unsigned short* __restrict__ residB,
    const float* __restrict__ mask,
    unsigned short* __restrict__ outB, float* __restrict__ outCM, Outs3 outs)
{
    constexpr int K = KSTEPS * 64;
    __shared__ __align__(16) unsigned short As[128 * 64];
    __shared__ __align__(16) unsigned short Xs[128 * 64];

    const int tid  = threadIdx.x;
    const int b    = blockIdx.z;
    const int m0   = blockIdx.y * 128;
    const int t0   = blockIdx.x * 128;
    const int wid  = tid >> 6, lane = tid & 63;
    const int wm   = (wid >> 1) * 64;
    const int wt   = (wid & 1) * 64;
    const int lanerow = lane & 15, laneoct = lane >> 4;

    int ldsOff[4];
    const unsigned short* gW[4];
    const unsigned short* gX[4];
    #pragma unroll
    for (int it = 0; it < 4; ++it) {
        const int idx = it * 256 + tid;
        const int row = idx >> 3, c16 = idx & 7;
        ldsOff[it] = row * 64 + ((c16 * 8) ^ ((row & 7) * 8));
        const int arow = CMAJOR ? min(m0 + row, M - 1) : (m0 + row);
        gW[it] = W + (size_t)arow * K + c16 * 8;
        gX[it] = X + ((size_t)(b * TTIME) + t0 + row) * K + c16 * 8;
    }

    f32x4v acc[4][4];
    #pragma unroll
    for (int i = 0; i < 4; ++i)
        #pragma unroll
        for (int j = 0; j < 4; ++j) { acc[i][j][0]=0.f; acc[i][j][1]=0.f; acc[i][j][2]=0.f; acc[i][j][3]=0.f; }

    // depth-2 register staging: buf0 holds even steps, buf1 odd steps
    u16x8 ra0[4], rx0[4], ra1[4], rx1[4];
    #pragma unroll
    for (int it = 0; it < 4; ++it) {
        ra0[it] = *(const u16x8*)gW[it];
        rx0[it] = *(const u16x8*)gX[it];
    }
    if (KSTEPS > 1) {
        #pragma unroll
        for (int it = 0; it < 4; ++it) {
            ra1[it] = *(const u16x8*)(gW[it] + 64);
            rx1[it] = *(const u16x8*)(gX[it] + 64);
        }
    }

    #pragma unroll
    for (int ks = 0; ks < KSTEPS; ++ks) {
        // stage step ks from its register buffer (loaded at ks-2 / prologue)
        if ((ks & 1) == 0) {
            #pragma unroll
            for (int it = 0; it < 4; ++it) {
                *(u16x8*)&As[ldsOff[it]] = ra0[it];
                *(u16x8*)&Xs[ldsOff[it]] = rx0[it];
            }
        } else {
            #pragma unroll
            for (int it = 0; it < 4; ++it) {
                *(u16x8*)&As[ldsOff[it]] = ra1[it];
                *(u16x8*)&Xs[ldsOff[it]] = rx1[it];
            }
        }
        LDS_BARRIER();   // writes visible; prefetch loads remain in flight

        // prefetch step ks+2 into the buffer just written out
        if (ks + 2 < KSTEPS) {
            const int koff = (ks + 2) * 64;
            if ((ks & 1) == 0) {
                #pragma unroll
                for (int it = 0; it < 4; ++it) {
                    ra0[it] = *(const u16x8*)(gW[it] + koff);
                    rx0[it] = *(const u16x8*)(gX[it] + koff);
                }
            } else {
                #pragma unroll
                for (int it = 0; it < 4; ++it) {
                    ra1[it] = *(const u16x8*)(gW[it] + koff);
                    rx1[it] = *(const u16x8*)(gX[it] + koff);
                }
            }
        }

        #pragma unroll
        for (int ksub = 0; ksub < 2; ++ksub) {
            const int xk = (ksub * 32 + laneoct * 8) ^ ((lanerow & 7) * 8);
            bf16x8 af[4], bfr[4];
            #pragma unroll
            for (int m = 0; m < 4; ++m)
                af[m] = *(const bf16x8*)&As[(wm + m * 16 + lanerow) * 64 + xk];
            #pragma unroll
            for (int n = 0; n < 4; ++n)
                bfr[n] = *(const bf16x8*)&Xs[(wt + n * 16 + lanerow) * 64 + xk];
            #pragma unroll
            for (int m = 0; m < 4; ++m)
                #pragma unroll
                for (int n = 0; n < 4; ++n)
                    acc[m][n] = __builtin_amdgcn_mfma_f32_16x16x32_bf16(af[m], bfr[n], acc[m][n], 0, 0, 0);
        }
        LDS_BARRIER();   // all reads of this tile done before next overwrite
    }

    // epilogue: D row (m) = laneoct*4 + r, col (t) = lanerow
    #pragma unroll
    for (int msub = 0; msub < 4; ++msub) {
        const int mq = m0 + wm + msub * 16 + laneoct * 4;
        float b0 = 0.f, b1 = 0.f, b2 = 0.f, b3 = 0.f;
        if (HAS_BIAS) {
            if (CMAJOR) {
                b0 = (mq + 0 < M) ? bias[mq + 0] : 0.f;
                b1 = (mq + 1 < M) ? bias[mq + 1] : 0.f;
                b2 = (mq + 2 < M) ? bias[mq + 2] : 0.f;
                b3 = (mq + 3 < M) ? bias[mq + 3] : 0.f;
            } else {
                const float4 bq = *(const float4*)&bias[mq];
                b0 = bq.x; b1 = bq.y; b2 = bq.z; b3 = bq.w;
            }
        }
        #pragma unroll
        for (int tsub = 0; tsub < 4; ++tsub) {
            const int t = t0 + wt + tsub * 16 + lanerow;
            float v0 = acc[msub][tsub][0] + b0;
            float v1 = acc[msub][tsub][1] + b1;
            float v2 = acc[msub][tsub][2] + b2;
            float v3 = acc[msub][tsub][3] + b3;
            if (HAS_RESID) {
                const u16x4 rv = *(const u16x4*)(residB + ((size_t)(b * TTIME + t)) * FMC + mq);
                v0 += b2f((unsigned short)rv[0]); v1 += b2f((unsigned short)rv[1]);
                v2 += b2f((unsigned short)rv[2]); v3 += b2f((unsigned short)rv[3]);
            }
            if (HAS_MASK) {
                const float mv = mask[b * TTIME + t];
                v0 *= mv; v1 *= mv; v2 *= mv; v3 *= mv;
            }
            if (CMAJOR) {
                if (mq + 0 < M) outCM[((size_t)(b * M + mq + 0)) * TTIME + t] = v0;
                if (mq + 1 < M) outCM[((size_t)(b * M + mq + 1)) * TTIME + t] = v1;
                if (mq + 2 < M) outCM[((size_t)(b * M + mq + 2)) * TTIME + t] = v2;
                if (mq + 3 < M) outCM[((size_t)(b * M + mq + 3)) * TTIME + t] = v3;
            } else if (SPLIT == 2) {
                if (mq < 3 * FMC) {
                    const unsigned long long pk =
                        (unsigned long long)f2b(v0) | ((unsigned long long)f2b(v1) << 16) |
                        ((unsigned long long)f2b(v2) << 32) | ((unsigned long long)f2b(v3) << 48);
                    const int sel = mq >> 9;
                    const int mi = mq & 511;
                    *(unsigned long long*)(outs.p[sel] + ((size_t)(b * TTIME + t)) * FMC + mi) = pk;
                } else if (mq < 3 * FMC + NHEAD * NTOK) {
                    const int hl = mq - 3 * FMC;
                    float* sp = outCM + ((size_t)(b * NHEAD * NTOK + hl)) * TTIME + t;
                    sp[0] = v0; sp[TTIME] = v1; sp[2 * TTIME] = v2; sp[3 * TTIME] = v3;
                }
            } else {
                const unsigned long long pk =
                    (unsigned long long)f2b(v0) | ((unsigned long long)f2b(v1) << 16) |
                    ((unsigned long long)f2b(v2) << 32) | ((unsigned long long)f2b(v3) << 48);
                *(unsigned long long*)(outB + ((size_t)(b * TTIME + t)) * FMC + mq) = pk;
            }
        }
    }
}

// ---------------------------------------------------------------------------
__global__ __launch_bounds__(256) void transpose_x(
    const float* __restrict__ x, unsigned short* __restrict__ xT)
{
    __shared__ float tile[64][65];
    const int b = blockIdx.z, d0 = blockIdx.y * 64, t0 = blockIdx.x * 64;
    const int tx = threadIdx.x & 63, ty = threadIdx.x >> 6;
    #pragma unroll
    for (int i = 0; i < 64; i += 4)
        tile[ty + i][tx] = x[((size_t)(b * DIMX + d0 + ty + i)) * TTIME + t0 + tx];
    __syncthreads();
    #pragma unroll
    for (int i = 0; i < 64; i += 4)
        xT[((size_t)(b * TTIME + t0 + ty + i)) * DIMX + d0 + tx] = f2b(tile[tx][ty + i]);
}

// fused 5-way f32 -> bf16 weight conversion (one launch)
__global__ __launch_bounds__(256) void to_bf16_multi(
    const float* __restrict__ s0, unsigned short* __restrict__ d0, int n0,
    const float* __restrict__ s1, unsigned short* __restrict__ d1, int n1,
    const float* __restrict__ s2, unsigned short* __restrict__ d2, int n2,
    const float* __restrict__ s3, unsigned short* __restrict__ d3, int n3,
    const float* __restrict__ s4, unsigned short* __restrict__ d4, int n4)
{
    int i = blockIdx.x * 256 + threadIdx.x;
    if (i < n0) { d0[i] = f2b(s0[i]); return; } i -= n0;
    if (i < n1) { d1[i] = f2b(s1[i]); return; } i -= n1;
    if (i < n2) { d2[i] = f2b(s2[i]); return; } i -= n2;
    if (i < n3) { d3[i] = f2b(s3[i]); return; } i -= n3;
    if (i < n4) { d4[i] = f2b(s4[i]); }
}

// Wcat rows: [0,512) dq, [512,1024) dk, [1024,1536) dv, [1536,1576) qkh, rest 0
__global__ void build_wcat(const float* __restrict__ dq, const float* __restrict__ dk,
                           const float* __restrict__ dv, const unsigned short* __restrict__ qkh,
                           unsigned short* __restrict__ Wcat)
{
    const int total = NLAYERS * WROWS * 512;
    for (int idx = blockIdx.x * 256 + threadIdx.x; idx < total; idx += gridDim.x * 256) {
        const int i = idx / (WROWS * 512);
        const int r = (idx >> 9) % WROWS;
        const int c = idx & 511;
        unsigned short v;
        if (r < 512)        v = f2b(dq[((size_t)i * 512 + r) * 512 + c]);
        else if (r < 1024)  v = f2b(dk[((size_t)i * 512 + (r - 512)) * 512 + c]);
        else if (r < 1536)  v = f2b(dv[((size_t)i * 512 + (r - 1024)) * 512 + c]);
        else if (r < 1576)  v = qkh[(r - 1536) * 512 + c];
        else                v = 0;
        Wcat[idx] = v;
    }
}

// qkh[(h*10+l)][c] = (1/sqrt(128)) * sum_d qtok[l][128h+d] * Wk[128h+d][c], bf16
__global__ __launch_bounds__(256) void qkh_build(
    const float* __restrict__ qtok, const float* __restrict__ sm_in_w,
    unsigned short* __restrict__ qkh)
{
    const int hl = blockIdx.x;
    const int h = hl / NTOK, l = hl % NTOK;
    __shared__ float q[128];
    if (threadIdx.x < 128) q[threadIdx.x] = qtok[l * FMC + h * 128 + threadIdx.x];
    __syncthreads();
    for (int c = threadIdx.x; c < FMC; c += 256) {
        float acc = 0.f;
        const float* wr = sm_in_w + (size_t)(FMC + h * 128) * FMC + c;
        #pragma unroll 4
        for (int d = 0; d < 128; ++d) acc += q[d] * wr[(size_t)d * FMC];
        qkh[hl * FMC + c] = f2b(acc * 0.08838834764831845f);
    }
}

// fast projection: out[r,e] = bias_scale*bias[e] + scale * sum_d in[r,d]*W[e,d]
__global__ __launch_bounds__(256) void fast_proj(
    const float* __restrict__ in, const float* __restrict__ W, const float* __restrict__ bias,
    float* __restrict__ out, int outStride, float scale, float bias_scale)
{
    const int r = blockIdx.y;
    const int w = threadIdx.x >> 6, lane = threadIdx.x & 63;
    const int e = blockIdx.x * 4 + w;
    const float4 a0 = *(const float4*)&in[(size_t)r * FMC + lane * 8];
    const float4 a1 = *(const float4*)&in[(size_t)r * FMC + lane * 8 + 4];
    const float4 w0 = *(const float4*)&W[(size_t)e * FMC + lane * 8];
    const float4 w1 = *(const float4*)&W[(size_t)e * FMC + lane * 8 + 4];
    float s = a0.x*w0.x + a0.y*w0.y + a0.z*w0.z + a0.w*w0.w
            + a1.x*w1.x + a1.y*w1.y + a1.z*w1.z + a1.w*w1.w;
    #pragma unroll
    for (int off = 32; off; off >>= 1) s += __shfl_xor(s, off);
    if (lane == 0)
        out[(size_t)r * outStride + e] = bias_scale * (bias ? bias[e] : 0.f) + scale * s;
}

// O[b,l,e] = 5*bv[e] + sum_c Wv[e,c] * G[b,h(e),l,c]    (deferred summary, Wv pass)
__global__ __launch_bounds__(256) void fast_sm_ov(
    const float* __restrict__ G, const float* __restrict__ sm_in_w,
    const float* __restrict__ sm_in_b, float* __restrict__ O)
{
    const int r = blockIdx.y;                 // b*NTOK + l
    const int b = r / NTOK, l = r % NTOK;
    const int w = threadIdx.x >> 6, lane = threadIdx.x & 63;
    const int e = blockIdx.x * 4 + w;
    const int h = e >> 7;
    const float* gin = G + (((size_t)(b * NHEAD + h)) * NTOK + l) * FMC;
    const float* wr  = sm_in_w + (size_t)(2 * FMC + e) * FMC;
    const float4 a0 = *(const float4*)&gin[lane * 8];
    const float4 a1 = *(const float4*)&gin[lane * 8 + 4];
    const float4 w0 = *(const float4*)&wr[lane * 8];
    const float4 w1 = *(const float4*)&wr[lane * 8 + 4];
    float s = a0.x*w0.x + a0.y*w0.y + a0.z*w0.z + a0.w*w0.w
            + a1.x*w1.x + a1.y*w1.y + a1.z*w1.z + a1.w*w1.w;
    #pragma unroll
    for (int off = 32; off; off >>= 1) s += __shfl_xor(s, off);
    if (lane == 0)
        O[(size_t)r * FMC + e] = 5.0f * sm_in_b[2 * FMC + e] + s;
}

// gpart[b][seg][h][l][c] = sum_{t in seg} exp(s - m_seg) * trunk[b,t,c]
// + segstats (m_seg, sum_seg).  Online softmax: no global stats pass needed.
__global__ __launch_bounds__(256) void g_accum_part(
    const float* __restrict__ scores, const unsigned short* __restrict__ trunkB,
    float* __restrict__ gpart, float2* __restrict__ segstats)
{
    const int seg = blockIdx.x, b = blockIdx.y;
    const int h = threadIdx.x >> 6, lane = threadIdx.x & 63;
    const int c0 = lane * 8;
    const float* ap = scores + ((size_t)(b * NHEAD + h)) * NTOK * TTIME + seg * 64;
    float m_[NTOK];
    #pragma unroll
    for (int l = 0; l < NTOK; ++l) {
        float v = ap[(size_t)l * TTIME + lane];
        #pragma unroll
        for (int off = 32; off; off >>= 1) v = fmaxf(v, __shfl_xor(v, off));
        m_[l] = v;
    }
    float sum_[NTOK];
    float acc[NTOK][8];
    #pragma unroll
    for (int l = 0; l < NTOK; ++l) {
        sum_[l] = 0.f;
        #pragma unroll
        for (int j = 0; j < 8; ++j) acc[l][j] = 0.f;
    }
    const unsigned short* tp = trunkB + ((size_t)(b * TTIME) + seg * 64) * FMC + c0;
    #pragma unroll 2
    for (int tt = 0; tt < 64; ++tt) {
        const u16x8 tv = *(const u16x8*)(tp + (size_t)tt * FMC);
        float tf[8];
        #pragma unroll
        for (int j = 0; j < 8; ++j) tf[j] = b2f((unsigned short)tv[j]);
        #pragma unroll
        for (int l = 0; l < NTOK; ++l) {
            const float a = __expf(ap[(size_t)l * TTIME + tt] - m_[l]);
            sum_[l] += a;
            #pragma unroll
            for (int j = 0; j < 8; ++j) acc[l][j] += a * tf[j];
        }
    }
    float* gp = gpart + ((((size_t)(b * NSEG) + seg) * NHEAD + h) * NTOK) * FMC + c0;
    #pragma unroll
    for (int l = 0; l < NTOK; ++l) {
        *(float4*)&gp[(size_t)l * FMC + 0] = *(float4*)&acc[l][0];
        *(float4*)&gp[(size_t)l * FMC + 4] = *(float4*)&acc[l][4];
    }
    if (lane == 0) {
        float2* st = segstats + (((size_t)(b * NSEG) + seg) * NHEAD + h) * NTOK;
        #pragma unroll
        for (int l = 0; l < NTOK; ++l) { float2 s; s.x = m_[l]; s.y = sum_[l]; st[l] = s; }
    }
}

// G[b][hl][c] (+)= softmax-normalized combine of gpart across segments.
__global__ __launch_bounds__(256) void g_reduce(
    const float* __restrict__ gpart, const float2* __restrict__ segstats,
    float* __restrict__ G, int first)
{
    const int tid = threadIdx.x;
    const int c = blockIdx.x * 256 + tid;
    const int hl = blockIdx.y;
    const int b = blockIdx.z;
    const int h = hl / NTOK, l = hl % NTOK;
    __shared__ float2 st[NSEG];
    if (tid < NSEG)
        st[tid] = segstats[(((size_t)(b * NSEG) + tid) * NHEAD + h) * NTOK + l];
    __syncthreads();
    float m = -1e30f;
    #pragma unroll 8
    for (int s = 0; s < NSEG; ++s) m = fmaxf(m, st[s].x);
    float denom = 0.f;
    #pragma unroll 8
    for (int s = 0; s < NSEG; ++s) denom += __expf(st[s].x - m) * st[s].y;
    const float invd = 1.0f / denom;
    const float* p = gpart + (((size_t)(b * NSEG) * NHEAD + h) * NTOK + l) * FMC + c;
    const size_t stride = (size_t)NHEAD * NTOK * FMC;
    float acc = 0.f;
    #pragma unroll 4
    for (int s = 0; s < NSEG; ++s) acc += __expf(st[s].x - m) * p[s * stride];
    const float r = acc * invd;
    const size_t id = ((size_t)(b * NHEAD * NTOK) + hl) * FMC + c;
    G[id] = first ? r : (G[id] + r);
}

// dilated 3-tap attention, channel-last bf16; H may alias Q
__global__ __launch_bounds__(256) void dal_elem_cl(
    const unsigned short* __restrict__ Q, const unsigned short* __restrict__ K,
    const unsigned short* __restrict__ V, const float* __restrict__ rel,
    unsigned short* __restrict__ H, int dil)
{
    __shared__ float rels[FMC * 3];
    for (int i = threadIdx.x; i < FMC * 3; i += 256) rels[i] = rel[i];
    __syncthreads();
    const int g = blockIdx.x * 256 + threadIdx.x;
    const int c8 = g & 63;
    const int t = (g >> 6) & (TTIME - 1);
    const int b = g >> 18;
    const size_t base = ((size_t)(b * TTIME + t)) * FMC + c8 * 8;
    const u16x8 q8 = *(const u16x8*)(Q + base);
    const u16x8 k1 = *(const u16x8*)(K + base);
    const u16x8 v1 = *(const u16x8*)(V + base);
    u16x8 k0 = {0,0,0,0,0,0,0,0}, v0 = k0, k2 = k0, v2 = k0;
    const bool in0 = (t - dil) >= 0, in2 = (t + dil) < TTIME;
    if (in0) { k0 = *(const u16x8*)(K + base - (size_t)dil * FMC); v0 = *(const u16x8*)(V + base - (size_t)dil * FMC); }
    if (in2) { k2 = *(const u16x8*)(K + base + (size_t)dil * FMC); v2 = *(const u16x8*)(V + base + (size_t)dil * FMC); }
    u16x8 out;
    #pragma unroll
    for (int j = 0; j < 8; ++j) {
        const int c = c8 * 8 + j;
        const float q = b2f((unsigned short)q8[j]);
        const float kk0 = b2f((unsigned short)k0[j]);
        const float kk1 = b2f((unsigned short)k1[j]);
        const float kk2 = b2f((unsigned short)k2[j]);
        const float vv0 = b2f((unsigned short)v0[j]) + rels[c * 3 + 0];
        const float vv1 = b2f((unsigned short)v1[j]) + rels[c * 3 + 1];
        const float vv2 = b2f((unsigned short)v2[j]) + rels[c * 3 + 2];
        const float s0 = q * kk0, s1 = q * kk1, s2 = q * kk2;
        const float m = fmaxf(s0, fmaxf(s1, s2));
        const float e0 = __expf(s0 - m), e1 = __expf(s1 - m), e2 = __expf(s2 - m);
        const float hres = (e0 * vv0 + e1 * vv1 + e2 * vv2) / (e0 + e1 + e2);
        out[j] = (short)f2b(fmaxf(hres, 0.f));
    }
    *(u16x8*)(H + base) = out;
}

// final cross attention: per (b,h,t): scores vs 10 keys -> softmax -> AV
// kvh layout [b*NTOK+l][1024]: [0,512) = kh, [512,1024) = vh
__global__ __launch_bounds__(256) void ca_fused_t(
    const unsigned short* __restrict__ Qc, const float* __restrict__ kvh,
    unsigned short* __restrict__ o_c)
{
    const int b = blockIdx.z, h = blockIdx.y;
    __shared__ float kh[NTOK][128];
    __shared__ float vh[NTOK][128];
    for (int i = threadIdx.x; i < NTOK * 128; i += 256) {
        const int l = i >> 7, d = i & 127;
        kh[l][d] = kvh[((size_t)(b * NTOK) + l) * 1024 + h * 128 + d];
        vh[l][d] = kvh[((size_t)(b * NTOK) + l) * 1024 + 512 + h * 128 + d];
    }
    __syncthreads();
    const int t = blockIdx.x * 256 + threadIdx.x;
    const unsigned short* qp = Qc + ((size_t)(b * TTIME + t)) * FMC + h * 128;
    float s[NTOK];
    #pragma unroll
    for (int l = 0; l < NTOK; ++l) s[l] = 0.f;
    #pragma unroll
    for (int d0 = 0; d0 < 128; d0 += 8) {
        const u16x8 qv = *(const u16x8*)(qp + d0);
        float qf[8];
        #pragma unroll
        for (int j = 0; j < 8; ++j) qf[j] = b2f((unsigned short)qv[j]);
        #pragma unroll
        for (int l = 0; l < NTOK; ++l) {
            float a = 0.f;
            #pragma unroll
            for (int j = 0; j < 8; ++j) a += qf[j] * kh[l][d0 + j];
            s[l] += a;
        }
    }
    float mx = -1e30f;
    #pragma unroll
    for (int l = 0; l < NTOK; ++l) { s[l] *= 0.08838834764831845f; mx = fmaxf(mx, s[l]); }
    float sum = 0.f;
    #pragma unroll
    for (int l = 0; l < NTOK; ++l) { s[l] = __expf(s[l] - mx); sum += s[l]; }
    const float inv = 1.0f / sum;
    #pragma unroll
    for (int l = 0; l < NTOK; ++l) s[l] *= inv;
    unsigned short* op = o_c + ((size_t)(b * TTIME + t)) * FMC + h * 128;
    #pragma unroll
    for (int d0 = 0; d0 < 128; d0 += 8) {
        u16x8 o8;
        #pragma unroll
        for (int j = 0; j < 8; ++j) {
            float o = 0.f;
            #pragma unroll
            for (int l = 0; l < NTOK; ++l) o += s[l] * vh[l][d0 + j];
            o8[j] = (short)f2b(o);
        }
        *(u16x8*)(op + d0) = o8;
    }
}

// ---------------------------------------------------------------------------
extern "C" void kernel_launch(void* const* d_in, const int* in_sizes, int n_in,
                              void* d_out, int out_size, void* d_ws, size_t ws_size,
                              hipStream_t stream)
{
    const float* x        = (const float*)d_in[0];
    const float* mask     = (const float*)d_in[1];
    const float* cw1      = (const float*)d_in[2];
    const float* cb1      = (const float*)d_in[3];
    const float* dal_q    = (const float*)d_in[4];
    const float* dal_k    = (const float*)d_in[5];
    const float* dal_v    = (const float*)d_in[6];
    const float* rel_t    = (const float*)d_in[7];
    const float* blk_w    = (const float*)d_in[8];
    const float* blk_b    = (const float*)d_in[9];
    const float* cow      = (const float*)d_in[10];
    const float* cob      = (const float*)d_in[11];
    const float* tokens   = (const float*)d_in[12];
    const float* sm_in_w  = (const float*)d_in[13];
    const float* sm_in_b  = (const float*)d_in[14];
    const float* sm_out_w = (const float*)d_in[15];
    const float* sm_out_b = (const float*)d_in[16];
    const float* ca_in_w  = (const float*)d_in[17];
    const float* ca_out_w = (const float*)d_in[18];
    (void)in_sizes; (void)n_in; (void)out_size; (void)ws_size;

    const size_t BIG = (size_t)BBATCH * FMC * TTIME;   // 16.7M elems
    char* ws = (char*)d_ws;
    size_t off = 0;
    auto alloc = [&](size_t nbytes) {
        void* p = (void*)(ws + off);
        off = (off + nbytes + 255) & ~(size_t)255;
        return p;
    };
    unsigned short* trunkB  = (unsigned short*)alloc(BIG * 2);   // bf16 trunk (only copy)
    unsigned short* bufQ    = (unsigned short*)alloc(BIG * 2);   // q -> h ; (xT low)
    unsigned short* bufK    = (unsigned short*)alloc(BIG * 2);   // k ; Qc  ; (xT high)
    unsigned short* bufV    = (unsigned short*)alloc(BIG * 2);   // v ; o_c
    float* scores  = (float*)alloc((size_t)BBATCH * NHEAD * NTOK * TTIME * 4);
    float* gpart   = (float*)alloc((size_t)BBATCH * NSEG * NHEAD * NTOK * FMC * 4);
    float2* sstats = (float2*)alloc((size_t)BBATCH * NSEG * NHEAD * NTOK * 8);
    float* G       = (float*)alloc((size_t)BBATCH * NHEAD * NTOK * FMC * 4);
    float* qtok    = (float*)alloc((size_t)NTOK * FMC * 4);
    float* Osum    = (float*)alloc((size_t)BBATCH * NTOK * FMC * 4);
    float* summ5   = (float*)alloc((size_t)BBATCH * NTOK * FMC * 4);
    float* kvh     = (float*)alloc((size_t)BBATCH * NTOK * 1024 * 4);
    unsigned short* Wc   = (unsigned short*)alloc((size_t)FMC * DIMX * 2);
    unsigned short* Wcat = (unsigned short*)alloc((size_t)NLAYERS * WROWS * FMC * 2);
    unsigned short* Wblk = (unsigned short*)alloc((size_t)NLAYERS * FMC * FMC * 2);
    unsigned short* Wqca = (unsigned short*)alloc((size_t)FMC * FMC * 2);
    unsigned short* Wcao = (unsigned short*)alloc((size_t)FMC * FMC * 2);
    unsigned short* Wcow = (unsigned short*)alloc((size_t)NCC * FMC * 2);
    unsigned short* qkh  = (unsigned short*)alloc((size_t)NHEAD * NTOK * FMC * 2);
    unsigned short* xT = bufQ;  // spans bufQ+bufK (contiguous), dead after conv

    const Outs3 no3 = {};

    // --- weight conversion / precompute ---
    {
        const int n0 = FMC * DIMX, n1 = FMC * FMC, n2 = FMC * FMC,
                  n3 = NCC * FMC, n4 = NLAYERS * FMC * FMC;
        const int total = n0 + n1 + n2 + n3 + n4;
        hipLaunchKernelGGL(to_bf16_multi, dim3((total + 255) / 256), dim3(256), 0, stream,
                           cw1, Wc, n0, ca_in_w, Wqca, n1, ca_out_w, Wcao, n2,
                           cow, Wcow, n3, blk_w, Wblk, n4);
    }
    // qtok = tokens @ wq^T + bq   (rows = 10)
    hipLaunchKernelGGL(fast_proj, dim3(FMC / 4, NTOK), dim3(256), 0, stream,
                       tokens, sm_in_w, sm_in_b, qtok, FMC, 1.0f, 1.0f);
    hipLaunchKernelGGL(qkh_build, dim3(NHEAD * NTOK), dim3(256), 0, stream, qtok, sm_in_w, qkh);
    hipLaunchKernelGGL(build_wcat, dim3(2048), dim3(256), 0, stream, dal_q, dal_k, dal_v, qkh, Wcat);

    // --- input transpose + conv ---
    hipLaunchKernelGGL(transpose_x, dim3(TTIME / 64, DIMX / 64, BBATCH), dim3(256), 0, stream, x, xT);
    hipLaunchKernelGGL((gemm_mfma<16,1,0,0,0,0>), dim3(TTIME / 128, FMC / 128, BBATCH), dim3(256), 0, stream,
                       Wc, xT, FMC, cb1, nullptr, nullptr, trunkB, nullptr, no3);

    for (int i = 0; i < NLAYERS; ++i) {
        const int dil = 1 << i;
        // fused projections + summary scores: {q,k,v,scores} = Wcat[i] @ trunk
        Outs3 o3; o3.p[0] = bufQ; o3.p[1] = bufK; o3.p[2] = bufV;
        hipLaunchKernelGGL((gemm_mfma<8,0,0,0,2,0>), dim3(TTIME / 128, WROWS / 128, BBATCH), dim3(256), 0, stream,
                           Wcat + (size_t)i * WROWS * FMC, trunkB, 3 * FMC + NHEAD * NTOK,
                           nullptr, nullptr, nullptr, nullptr, scores, o3);
        // summary path: online-softmax partial accumulation, combine + layer-accumulate
        hipLaunchKernelGGL(g_accum_part, dim3(NSEG, BBATCH), dim3(256), 0, stream,
                           scores, trunkB, gpart, sstats);
        hipLaunchKernelGGL(g_reduce, dim3(FMC / 256, NHEAD * NTOK, BBATCH), dim3(256), 0, stream,
                           gpart, sstats, G, (i == 0) ? 1 : 0);
        // dilated attention (h aliases q in bufQ)
        hipLaunchKernelGGL(dal_elem_cl, dim3((unsigned)(BIG / 256 / 8)), dim3(256), 0, stream,
                           bufQ, bufK, bufV, rel_t + (size_t)i * FMC * 3, bufQ, dil);
        // trunk = (trunk + blk_w @ h + blk_b) * mask   (in-place bf16 resid)
        hipLaunchKernelGGL((gemm_mfma<8,1,1,1,0,0>), dim3(TTIME / 128, FMC / 128, BBATCH), dim3(256), 0, stream,
                           Wblk + (size_t)i * FMC * FMC, bufQ, FMC,
                           blk_b + (size_t)i * FMC, trunkB, mask, trunkB, nullptr, no3);
    }

    // --- deferred summary (linear): O = Wv@G + 5bv ; summ5 = sm_out(O)/5 ; kvh ---
    hipLaunchKernelGGL(fast_sm_ov, dim3(FMC / 4, BBATCH * NTOK), dim3(256), 0, stream,
                       G, sm_in_w, sm_in_b, Osum);
    hipLaunchKernelGGL(fast_proj, dim3(FMC / 4, BBATCH * NTOK), dim3(256), 0, stream,
                       Osum, sm_out_w, sm_out_b, summ5, FMC, 0.2f, 1.0f);
    hipLaunchKernelGGL(fast_proj, dim3(1024 / 4, BBATCH * NTOK), dim3(256), 0, stream,
                       summ5, ca_in_w + (size_t)FMC * FMC, nullptr, kvh, 1024, 1.0f, 0.0f);

    // --- final cross attention ---
    hipLaunchKernelGGL((gemm_mfma<8,0,0,0,0,0>), dim3(TTIME / 128, FMC / 128, BBATCH), dim3(256), 0, stream,
                       Wqca, trunkB, FMC, nullptr, nullptr, nullptr, bufK, nullptr, no3);
    hipLaunchKernelGGL(ca_fused_t, dim3(TTIME / 256, NHEAD, BBATCH), dim3(256), 0, stream,
                       bufK, kvh, bufV);
    // trunk += ca_out_w @ o_c   (in-place bf16 resid)
    hipLaunchKernelGGL((gemm_mfma<8,0,1,0,0,0>), dim3(TTIME / 128, FMC / 128, BBATCH), dim3(256), 0, stream,
                       Wcao, bufV, FMC, nullptr, trunkB, nullptr, trunkB, nullptr, no3);
    // d_out = (cow @ trunk + cob) * mask   (channel-major fp32)
    hipLaunchKernelGGL((gemm_mfma<8,1,0,1,0,1>), dim3(TTIME / 128, 2, BBATCH), dim3(256), 0, stream,
                       Wcow, trunkB, NCC, cob, nullptr, mask, nullptr, (float*)d_out, no3);
}

// Round 9
// 1308.268 us; speedup vs baseline: 1.2297x; 1.2297x over previous
//
#include <hip/hip_runtime.h>
#include <math.h>

#define FMC   512
#define DIMX  1024
#define NCC   157
#define NTOK  10
#define NHEAD 4
#define BBATCH 8
#define TTIME 4096
#define NLAYERS 5
#define NSEG  64
#define WROWS 1664   // 3*512 dal qkv + 40 qkh + 88 zero pad

typedef short bf16x8 __attribute__((ext_vector_type(8)));
typedef float f32x4v __attribute__((ext_vector_type(4)));
typedef unsigned short u16x8 __attribute__((ext_vector_type(8)));
typedef unsigned short u16x4 __attribute__((ext_vector_type(4)));

__device__ __forceinline__ float b2f(unsigned short u){
    union { unsigned int i; float f; } v; v.i = ((unsigned int)u) << 16; return v.f;
}
__device__ __forceinline__ unsigned short f2b(float f){
    union { float f; unsigned int i; } v; v.f = f;
    unsigned int r = v.i + 0x7FFFu + ((v.i >> 16) & 1u);
    return (unsigned short)(r >> 16);
}

struct Outs3 { unsigned short* p[3]; };

// ---------------------------------------------------------------------------
// MFMA GEMM: C[b,t,m] = sum_k W[m,k] * X[b,t,k]   (bf16 in, fp32 acc)
// Block 128m x 128t, BK=64, 4 waves (2x2). Reg-staged T14 pipeline (round-7
// verified): write regs->LDS ; barrier ; issue next-tile global loads (ride
// under MFMA) ; ds_read+MFMA ; barrier.  32KB LDS -> 5 blocks/CU.
// NEW: coalesced LDS-transpose epilogue for bf16 outputs — acc rounded into a
// [128t][128m] LDS tile (XOR-swizzled), then streamed out in 256B-contiguous
// chunks (resid read + mask applied coalesced). Kills the 1.6x write
// amplification of the old 8B/1KB-stride scatter.
// ---------------------------------------------------------------------------
template<int KSTEPS,int HAS_BIAS,int HAS_RESID,int HAS_MASK,int SPLIT,int CMAJOR>
__global__ __launch_bounds__(256) void gemm_mfma(
    const unsigned short* __restrict__ W, const unsigned short* __restrict__ X,
    int M,
    const float* __restrict__ bias, const unsigned short* __restrict__ residB,
    const float* __restrict__ mask,
    unsigned short* __restrict__ outB, float* __restrict__ outCM, Outs3 outs)
{
    constexpr int K = KSTEPS * 64;
    __shared__ __align__(16) unsigned short sh[2 * 128 * 64];  // As | Xs ; reused as C-tile
    unsigned short* As = sh;
    unsigned short* Xs = sh + 128 * 64;

    const int tid  = threadIdx.x;
    const int b    = blockIdx.z;
    const int m0   = blockIdx.y * 128;
    const int t0   = blockIdx.x * 128;
    const int wid  = tid >> 6, lane = tid & 63;
    const int wm   = (wid >> 1) * 64;
    const int wt   = (wid & 1) * 64;
    const int lanerow = lane & 15, laneoct = lane >> 4;

    int ldsOff[4];
    const unsigned short* gW[4];
    const unsigned short* gX[4];
    #pragma unroll
    for (int it = 0; it < 4; ++it) {
        const int idx = it * 256 + tid;
        const int row = idx >> 3, c16 = idx & 7;
        ldsOff[it] = row * 64 + ((c16 * 8) ^ ((row & 7) * 8));
        const int arow = CMAJOR ? min(m0 + row, M - 1) : (m0 + row);
        gW[it] = W + (size_t)arow * K + c16 * 8;
        gX[it] = X + ((size_t)(b * TTIME) + t0 + row) * K + c16 * 8;
    }

    f32x4v acc[4][4];
    #pragma unroll
    for (int i = 0; i < 4; ++i)
        #pragma unroll
        for (int j = 0; j < 4; ++j) { acc[i][j][0]=0.f; acc[i][j][1]=0.f; acc[i][j][2]=0.f; acc[i][j][3]=0.f; }

    u16x8 ra[4], rx[4];
    #pragma unroll
    for (int it = 0; it < 4; ++it) {
        ra[it] = *(const u16x8*)gW[it];
        rx[it] = *(const u16x8*)gX[it];
    }

    #pragma unroll
    for (int ks = 0; ks < KSTEPS; ++ks) {
        #pragma unroll
        for (int it = 0; it < 4; ++it) {
            *(u16x8*)&As[ldsOff[it]] = ra[it];
            *(u16x8*)&Xs[ldsOff[it]] = rx[it];
        }
        __syncthreads();
        if (ks + 1 < KSTEPS) {
            const int koff = (ks + 1) * 64;
            #pragma unroll
            for (int it = 0; it < 4; ++it) {
                ra[it] = *(const u16x8*)(gW[it] + koff);
                rx[it] = *(const u16x8*)(gX[it] + koff);
            }
        }
        #pragma unroll
        for (int ksub = 0; ksub < 2; ++ksub) {
            const int xk = (ksub * 32 + laneoct * 8) ^ ((lanerow & 7) * 8);
            bf16x8 af[4], bfr[4];
            #pragma unroll
            for (int m = 0; m < 4; ++m)
                af[m] = *(const bf16x8*)&As[(wm + m * 16 + lanerow) * 64 + xk];
            #pragma unroll
            for (int n = 0; n < 4; ++n)
                bfr[n] = *(const bf16x8*)&Xs[(wt + n * 16 + lanerow) * 64 + xk];
            #pragma unroll
            for (int m = 0; m < 4; ++m)
                #pragma unroll
                for (int n = 0; n < 4; ++n)
                    acc[m][n] = __builtin_amdgcn_mfma_f32_16x16x32_bf16(af[m], bfr[n], acc[m][n], 0, 0, 0);
        }
        __syncthreads();
    }

    // ---------------- epilogue ----------------
    // D fragment: row (m) = laneoct*4 + r, col (t) = lanerow.
    if (CMAJOR || (SPLIT == 2 && m0 >= 3 * FMC)) {
        // per-register path: channel-major fp32 (cow / scores rows)
        #pragma unroll
        for (int msub = 0; msub < 4; ++msub) {
            const int mq = m0 + wm + msub * 16 + laneoct * 4;
            float b0 = 0.f, b1 = 0.f, b2 = 0.f, b3 = 0.f;
            if (HAS_BIAS && CMAJOR) {
                b0 = (mq + 0 < M) ? bias[mq + 0] : 0.f;
                b1 = (mq + 1 < M) ? bias[mq + 1] : 0.f;
                b2 = (mq + 2 < M) ? bias[mq + 2] : 0.f;
                b3 = (mq + 3 < M) ? bias[mq + 3] : 0.f;
            }
            #pragma unroll
            for (int tsub = 0; tsub < 4; ++tsub) {
                const int t = t0 + wt + tsub * 16 + lanerow;
                float v0 = acc[msub][tsub][0] + b0;
                float v1 = acc[msub][tsub][1] + b1;
                float v2 = acc[msub][tsub][2] + b2;
                float v3 = acc[msub][tsub][3] + b3;
                if (HAS_MASK) {
                    const float mv = mask[b * TTIME + t];
                    v0 *= mv; v1 *= mv; v2 *= mv; v3 *= mv;
                }
                if (CMAJOR) {
                    if (mq + 0 < M) outCM[((size_t)(b * M + mq + 0)) * TTIME + t] = v0;
                    if (mq + 1 < M) outCM[((size_t)(b * M + mq + 1)) * TTIME + t] = v1;
                    if (mq + 2 < M) outCM[((size_t)(b * M + mq + 2)) * TTIME + t] = v2;
                    if (mq + 3 < M) outCM[((size_t)(b * M + mq + 3)) * TTIME + t] = v3;
                } else {
                    // scores rows [1536,1576): channel-major fp32
                    if (mq < 3 * FMC + NHEAD * NTOK) {
                        const int hl = mq - 3 * FMC;
                        float* sp = outCM + ((size_t)(b * NHEAD * NTOK + hl)) * TTIME + t;
                        sp[0] = v0; sp[TTIME] = v1; sp[2 * TTIME] = v2; sp[3 * TTIME] = v3;
                    }
                }
            }
        }
    } else {
        // coalesced path: round to bf16 into LDS [t][m] tile (swizzled), stream out
        unsigned short* tile = sh;
        #pragma unroll
        for (int msub = 0; msub < 4; ++msub) {
            const int mq = m0 + wm + msub * 16 + laneoct * 4;
            float b0 = 0.f, b1 = 0.f, b2 = 0.f, b3 = 0.f;
            if (HAS_BIAS) {
                const float4 bq = *(const float4*)&bias[mq];
                b0 = bq.x; b1 = bq.y; b2 = bq.z; b3 = bq.w;
            }
            const int ml = wm + msub * 16 + laneoct * 4;
            #pragma unroll
            for (int tsub = 0; tsub < 4; ++tsub) {
                const int tl = wt + tsub * 16 + lanerow;
                const unsigned long long pk =
                    (unsigned long long)f2b(acc[msub][tsub][0] + b0) |
                    ((unsigned long long)f2b(acc[msub][tsub][1] + b1) << 16) |
                    ((unsigned long long)f2b(acc[msub][tsub][2] + b2) << 32) |
                    ((unsigned long long)f2b(acc[msub][tsub][3] + b3) << 48);
                *(unsigned long long*)&tile[tl * 128 + (ml ^ ((tl & 7) * 8))] = pk;
            }
        }
        __syncthreads();
        #pragma unroll
        for (int it = 0; it < 8; ++it) {
            const int ci = it * 256 + tid;
            const int tl = ci >> 4, mc = ci & 15;
            const int t = t0 + tl;
            u16x8 v = *(const u16x8*)&tile[tl * 128 + ((mc * 8) ^ ((tl & 7) * 8))];
            if (HAS_RESID || HAS_MASK) {
                const float mv = HAS_MASK ? mask[b * TTIME + t] : 1.0f;
                u16x8 rv;
                if (HAS_RESID)
                    rv = *(const u16x8*)(residB + ((size_t)(b * TTIME + t)) * FMC + m0 + mc * 8);
                u16x8 o;
                #pragma unroll
                for (int j = 0; j < 8; ++j) {
                    float f = b2f((unsigned short)v[j]);
                    if (HAS_RESID) f += b2f((unsigned short)rv[j]);
                    o[j] = (short)f2b(f * mv);
                }
                v = o;
            }
            unsigned short* dst;
            if (SPLIT == 2) {
                const int gm = m0 + mc * 8;
                dst = outs.p[gm >> 9] + ((size_t)(b * TTIME + t)) * FMC + (gm & 511);
            } else {
                dst = outB + ((size_t)(b * TTIME + t)) * FMC + m0 + mc * 8;
            }
            *(u16x8*)dst = v;
        }
    }
}

// ---------------------------------------------------------------------------
__global__ __launch_bounds__(256) void transpose_x(
    const float* __restrict__ x, unsigned short* __restrict__ xT)
{
    __shared__ float tile[64][65];
    const int b = blockIdx.z, d0 = blockIdx.y * 64, t0 = blockIdx.x * 64;
    const int tx = threadIdx.x & 63, ty = threadIdx.x >> 6;
    #pragma unroll
    for (int i = 0; i < 64; i += 4)
        tile[ty + i][tx] = x[((size_t)(b * DIMX + d0 + ty + i)) * TTIME + t0 + tx];
    __syncthreads();
    #pragma unroll
    for (int i = 0; i < 64; i += 4)
        xT[((size_t)(b * TTIME + t0 + ty + i)) * DIMX + d0 + tx] = f2b(tile[tx][ty + i]);
}

// fused 5-way f32 -> bf16 weight conversion (one launch)
__global__ __launch_bounds__(256) void to_bf16_multi(
    const float* __restrict__ s0, unsigned short* __restrict__ d0, int n0,
    const float* __restrict__ s1, unsigned short* __restrict__ d1, int n1,
    const float* __restrict__ s2, unsigned short* __restrict__ d2, int n2,
    const float* __restrict__ s3, unsigned short* __restrict__ d3, int n3,
    const float* __restrict__ s4, unsigned short* __restrict__ d4, int n4)
{
    int i = blockIdx.x * 256 + threadIdx.x;
    if (i < n0) { d0[i] = f2b(s0[i]); return; } i -= n0;
    if (i < n1) { d1[i] = f2b(s1[i]); return; } i -= n1;
    if (i < n2) { d2[i] = f2b(s2[i]); return; } i -= n2;
    if (i < n3) { d3[i] = f2b(s3[i]); return; } i -= n3;
    if (i < n4) { d4[i] = f2b(s4[i]); }
}

// Wcat rows: [0,512) dq, [512,1024) dk, [1024,1536) dv, [1536,1576) qkh, rest 0
__global__ void build_wcat(const float* __restrict__ dq, const float* __restrict__ dk,
                           const float* __restrict__ dv, const unsigned short* __restrict__ qkh,
                           unsigned short* __restrict__ Wcat)
{
    const int total = NLAYERS * WROWS * 512;
    for (int idx = blockIdx.x * 256 + threadIdx.x; idx < total; idx += gridDim.x * 256) {
        const int i = idx / (WROWS * 512);
        const int r = (idx >> 9) % WROWS;
        const int c = idx & 511;
        unsigned short v;
        if (r < 512)        v = f2b(dq[((size_t)i * 512 + r) * 512 + c]);
        else if (r < 1024)  v = f2b(dk[((size_t)i * 512 + (r - 512)) * 512 + c]);
        else if (r < 1536)  v = f2b(dv[((size_t)i * 512 + (r - 1024)) * 512 + c]);
        else if (r < 1576)  v = qkh[(r - 1536) * 512 + c];
        else                v = 0;
        Wcat[idx] = v;
    }
}

// qkh[(h*10+l)][c] = (1/sqrt(128)) * sum_d qtok[l][128h+d] * Wk[128h+d][c], bf16
__global__ __launch_bounds__(256) void qkh_build(
    const float* __restrict__ qtok, const float* __restrict__ sm_in_w,
    unsigned short* __restrict__ qkh)
{
    const int hl = blockIdx.x;
    const int h = hl / NTOK, l = hl % NTOK;
    __shared__ float q[128];
    if (threadIdx.x < 128) q[threadIdx.x] = qtok[l * FMC + h * 128 + threadIdx.x];
    __syncthreads();
    for (int c = threadIdx.x; c < FMC; c += 256) {
        float acc = 0.f;
        const float* wr = sm_in_w + (size_t)(FMC + h * 128) * FMC + c;
        #pragma unroll 4
        for (int d = 0; d < 128; ++d) acc += q[d] * wr[(size_t)d * FMC];
        qkh[hl * FMC + c] = f2b(acc * 0.08838834764831845f);
    }
}

// fast projection: out[r,e] = bias_scale*bias[e] + scale * sum_d in[r,d]*W[e,d]
__global__ __launch_bounds__(256) void fast_proj(
    const float* __restrict__ in, const float* __restrict__ W, const float* __restrict__ bias,
    float* __restrict__ out, int outStride, float scale, float bias_scale)
{
    const int r = blockIdx.y;
    const int w = threadIdx.x >> 6, lane = threadIdx.x & 63;
    const int e = blockIdx.x * 4 + w;
    const float4 a0 = *(const float4*)&in[(size_t)r * FMC + lane * 8];
    const float4 a1 = *(const float4*)&in[(size_t)r * FMC + lane * 8 + 4];
    const float4 w0 = *(const float4*)&W[(size_t)e * FMC + lane * 8];
    const float4 w1 = *(const float4*)&W[(size_t)e * FMC + lane * 8 + 4];
    float s = a0.x*w0.x + a0.y*w0.y + a0.z*w0.z + a0.w*w0.w
            + a1.x*w1.x + a1.y*w1.y + a1.z*w1.z + a1.w*w1.w;
    #pragma unroll
    for (int off = 32; off; off >>= 1) s += __shfl_xor(s, off);
    if (lane == 0)
        out[(size_t)r * outStride + e] = bias_scale * (bias ? bias[e] : 0.f) + scale * s;
}

// O[b,l,e] = 5*bv[e] + sum_c Wv[e,c] * G[b,h(e),l,c]    (deferred summary, Wv pass)
__global__ __launch_bounds__(256) void fast_sm_ov(
    const float* __restrict__ G, const float* __restrict__ sm_in_w,
    const float* __restrict__ sm_in_b, float* __restrict__ O)
{
    const int r = blockIdx.y;                 // b*NTOK + l
    const int b = r / NTOK, l = r % NTOK;
    const int w = threadIdx.x >> 6, lane = threadIdx.x & 63;
    const int e = blockIdx.x * 4 + w;
    const int h = e >> 7;
    const float* gin = G + (((size_t)(b * NHEAD + h)) * NTOK + l) * FMC;
    const float* wr  = sm_in_w + (size_t)(2 * FMC + e) * FMC;
    const float4 a0 = *(const float4*)&gin[lane * 8];
    const float4 a1 = *(const float4*)&gin[lane * 8 + 4];
    const float4 w0 = *(const float4*)&wr[lane * 8];
    const float4 w1 = *(const float4*)&wr[lane * 8 + 4];
    float s = a0.x*w0.x + a0.y*w0.y + a0.z*w0.z + a0.w*w0.w
            + a1.x*w1.x + a1.y*w1.y + a1.z*w1.z + a1.w*w1.w;
    #pragma unroll
    for (int off = 32; off; off >>= 1) s += __shfl_xor(s, off);
    if (lane == 0)
        O[(size_t)r * FMC + e] = 5.0f * sm_in_b[2 * FMC + e] + s;
}

// gpart[b][seg][h][l][c] = bf16( sum_{t in seg} exp(s - m_seg) * trunk[b,t,c] )
// + segstats (m_seg, sum_seg).  Online softmax: no global stats pass needed.
__global__ __launch_bounds__(256) void g_accum_part(
    const float* __restrict__ scores, const unsigned short* __restrict__ trunkB,
    unsigned short* __restrict__ gpart, float2* __restrict__ segstats)
{
    const int seg = blockIdx.x, b = blockIdx.y;
    const int h = threadIdx.x >> 6, lane = threadIdx.x & 63;
    const int c0 = lane * 8;
    const float* ap = scores + ((size_t)(b * NHEAD + h)) * NTOK * TTIME + seg * 64;
    float m_[NTOK];
    #pragma unroll
    for (int l = 0; l < NTOK; ++l) {
        float v = ap[(size_t)l * TTIME + lane];
        #pragma unroll
        for (int off = 32; off; off >>= 1) v = fmaxf(v, __shfl_xor(v, off));
        m_[l] = v;
    }
    float sum_[NTOK];
    float acc[NTOK][8];
    #pragma unroll
    for (int l = 0; l < NTOK; ++l) {
        sum_[l] = 0.f;
        #pragma unroll
        for (int j = 0; j < 8; ++j) acc[l][j] = 0.f;
    }
    const unsigned short* tp = trunkB + ((size_t)(b * TTIME) + seg * 64) * FMC + c0;
    #pragma unroll 2
    for (int tt = 0; tt < 64; ++tt) {
        const u16x8 tv = *(const u16x8*)(tp + (size_t)tt * FMC);
        float tf[8];
        #pragma unroll
        for (int j = 0; j < 8; ++j) tf[j] = b2f((unsigned short)tv[j]);
        #pragma unroll
        for (int l = 0; l < NTOK; ++l) {
            const float a = __expf(ap[(size_t)l * TTIME + tt] - m_[l]);
            sum_[l] += a;
            #pragma unroll
            for (int j = 0; j < 8; ++j) acc[l][j] += a * tf[j];
        }
    }
    unsigned short* gp = gpart + ((((size_t)(b * NSEG) + seg) * NHEAD + h) * NTOK) * FMC + c0;
    #pragma unroll
    for (int l = 0; l < NTOK; ++l) {
        u16x8 o;
        #pragma unroll
        for (int j = 0; j < 8; ++j) o[j] = (short)f2b(acc[l][j]);
        *(u16x8*)&gp[(size_t)l * FMC] = o;
    }
    if (lane == 0) {
        float2* st = segstats + (((size_t)(b * NSEG) + seg) * NHEAD + h) * NTOK;
        #pragma unroll
        for (int l = 0; l < NTOK; ++l) { float2 s; s.x = m_[l]; s.y = sum_[l]; st[l] = s; }
    }
}

// G[b][hl][c] (+)= softmax-normalized combine of bf16 gpart across segments.
__global__ __launch_bounds__(256) void g_reduce(
    const unsigned short* __restrict__ gpart, const float2* __restrict__ segstats,
    float* __restrict__ G, int first)
{
    const int tid = threadIdx.x;
    const int c = blockIdx.x * 256 + tid;
    const int hl = blockIdx.y;
    const int b = blockIdx.z;
    const int h = hl / NTOK, l = hl % NTOK;
    __shared__ float2 st[NSEG];
    if (tid < NSEG)
        st[tid] = segstats[(((size_t)(b * NSEG) + tid) * NHEAD + h) * NTOK + l];
    __syncthreads();
    float m = -1e30f;
    #pragma unroll 8
    for (int s = 0; s < NSEG; ++s) m = fmaxf(m, st[s].x);
    float denom = 0.f;
    #pragma unroll 8
    for (int s = 0; s < NSEG; ++s) denom += __expf(st[s].x - m) * st[s].y;
    const float invd = 1.0f / denom;
    const unsigned short* p = gpart + (((size_t)(b * NSEG) * NHEAD + h) * NTOK + l) * FMC + c;
    const size_t stride = (size_t)NHEAD * NTOK * FMC;
    float acc = 0.f;
    #pragma unroll 4
    for (int s = 0; s < NSEG; ++s) acc += __expf(st[s].x - m) * b2f(p[s * stride]);
    const float r = acc * invd;
    const size_t id = ((size_t)(b * NHEAD * NTOK) + hl) * FMC + c;
    G[id] = first ? r : (G[id] + r);
}

// dilated 3-tap attention, channel-last bf16; H may alias Q
__global__ __launch_bounds__(256) void dal_elem_cl(
    const unsigned short* __restrict__ Q, const unsigned short* __restrict__ K,
    const unsigned short* __restrict__ V, const float* __restrict__ rel,
    unsigned short* __restrict__ H, int dil)
{
    __shared__ float rels[FMC * 3];
    for (int i = threadIdx.x; i < FMC * 3; i += 256) rels[i] = rel[i];
    __syncthreads();
    const int g = blockIdx.x * 256 + threadIdx.x;
    const int c8 = g & 63;
    const int t = (g >> 6) & (TTIME - 1);
    const int b = g >> 18;
    const size_t base = ((size_t)(b * TTIME + t)) * FMC + c8 * 8;
    const u16x8 q8 = *(const u16x8*)(Q + base);
    const u16x8 k1 = *(const u16x8*)(K + base);
    const u16x8 v1 = *(const u16x8*)(V + base);
    u16x8 k0 = {0,0,0,0,0,0,0,0}, v0 = k0, k2 = k0, v2 = k0;
    const bool in0 = (t - dil) >= 0, in2 = (t + dil) < TTIME;
    if (in0) { k0 = *(const u16x8*)(K + base - (size_t)dil * FMC); v0 = *(const u16x8*)(V + base - (size_t)dil * FMC); }
    if (in2) { k2 = *(const u16x8*)(K + base + (size_t)dil * FMC); v2 = *(const u16x8*)(V + base + (size_t)dil * FMC); }
    u16x8 out;
    #pragma unroll
    for (int j = 0; j < 8; ++j) {
        const int c = c8 * 8 + j;
        const float q = b2f((unsigned short)q8[j]);
        const float kk0 = b2f((unsigned short)k0[j]);
        const float kk1 = b2f((unsigned short)k1[j]);
        const float kk2 = b2f((unsigned short)k2[j]);
        const float vv0 = b2f((unsigned short)v0[j]) + rels[c * 3 + 0];
        const float vv1 = b2f((unsigned short)v1[j]) + rels[c * 3 + 1];
        const float vv2 = b2f((unsigned short)v2[j]) + rels[c * 3 + 2];
        const float s0 = q * kk0, s1 = q * kk1, s2 = q * kk2;
        const float m = fmaxf(s0, fmaxf(s1, s2));
        const float e0 = __expf(s0 - m), e1 = __expf(s1 - m), e2 = __expf(s2 - m);
        const float hres = (e0 * vv0 + e1 * vv1 + e2 * vv2) / (e0 + e1 + e2);
        out[j] = (short)f2b(fmaxf(hres, 0.f));
    }
    *(u16x8*)(H + base) = out;
}

// final cross attention: per (b,h,t): scores vs 10 keys -> softmax -> AV
// kvh layout [b*NTOK+l][1024]: [0,512) = kh, [512,1024) = vh
__global__ __launch_bounds__(256) void ca_fused_t(
    const unsigned short* __restrict__ Qc, const float* __restrict__ kvh,
    unsigned short* __restrict__ o_c)
{
    const int b = blockIdx.z, h = blockIdx.y;
    __shared__ float kh[NTOK][128];
    __shared__ float vh[NTOK][128];
    for (int i = threadIdx.x; i < NTOK * 128; i += 256) {
        const int l = i >> 7, d = i & 127;
        kh[l][d] = kvh[((size_t)(b * NTOK) + l) * 1024 + h * 128 + d];
        vh[l][d] = kvh[((size_t)(b * NTOK) + l) * 1024 + 512 + h * 128 + d];
    }
    __syncthreads();
    const int t = blockIdx.x * 256 + threadIdx.x;
    const unsigned short* qp = Qc + ((size_t)(b * TTIME + t)) * FMC + h * 128;
    float s[NTOK];
    #pragma unroll
    for (int l = 0; l < NTOK; ++l) s[l] = 0.f;
    #pragma unroll
    for (int d0 = 0; d0 < 128; d0 += 8) {
        const u16x8 qv = *(const u16x8*)(qp + d0);
        float qf[8];
        #pragma unroll
        for (int j = 0; j < 8; ++j) qf[j] = b2f((unsigned short)qv[j]);
        #pragma unroll
        for (int l = 0; l < NTOK; ++l) {
            float a = 0.f;
            #pragma unroll
            for (int j = 0; j < 8; ++j) a += qf[j] * kh[l][d0 + j];
            s[l] += a;
        }
    }
    float mx = -1e30f;
    #pragma unroll
    for (int l = 0; l < NTOK; ++l) { s[l] *= 0.08838834764831845f; mx = fmaxf(mx, s[l]); }
    float sum = 0.f;
    #pragma unroll
    for (int l = 0; l < NTOK; ++l) { s[l] = __expf(s[l] - mx); sum += s[l]; }
    const float inv = 1.0f / sum;
    #pragma unroll
    for (int l = 0; l < NTOK; ++l) s[l] *= inv;
    unsigned short* op = o_c + ((size_t)(b * TTIME + t)) * FMC + h * 128;
    #pragma unroll
    for (int d0 = 0; d0 < 128; d0 += 8) {
        u16x8 o8;
        #pragma unroll
        for (int j = 0; j < 8; ++j) {
            float o = 0.f;
            #pragma unroll
            for (int l = 0; l < NTOK; ++l) o += s[l] * vh[l][d0 + j];
            o8[j] = (short)f2b(o);
        }
        *(u16x8*)(op + d0) = o8;
    }
}

// ---------------------------------------------------------------------------
extern "C" void kernel_launch(void* const* d_in, const int* in_sizes, int n_in,
                              void* d_out, int out_size, void* d_ws, size_t ws_size,
                              hipStream_t stream)
{
    const float* x        = (const float*)d_in[0];
    const float* mask     = (const float*)d_in[1];
    const float* cw1      = (const float*)d_in[2];
    const float* cb1      = (const float*)d_in[3];
    const float* dal_q    = (const float*)d_in[4];
    const float* dal_k    = (const float*)d_in[5];
    const float* dal_v    = (const float*)d_in[6];
    const float* rel_t    = (const float*)d_in[7];
    const float* blk_w    = (const float*)d_in[8];
    const float* blk_b    = (const float*)d_in[9];
    const float* cow      = (const float*)d_in[10];
    const float* cob      = (const float*)d_in[11];
    const float* tokens   = (const float*)d_in[12];
    const float* sm_in_w  = (const float*)d_in[13];
    const float* sm_in_b  = (const float*)d_in[14];
    const float* sm_out_w = (const float*)d_in[15];
    const float* sm_out_b = (const float*)d_in[16];
    const float* ca_in_w  = (const float*)d_in[17];
    const float* ca_out_w = (const float*)d_in[18];
    (void)in_sizes; (void)n_in; (void)out_size; (void)ws_size;

    const size_t BIG = (size_t)BBATCH * FMC * TTIME;   // 16.7M elems
    char* ws = (char*)d_ws;
    size_t off = 0;
    auto alloc = [&](size_t nbytes) {
        void* p = (void*)(ws + off);
        off = (off + nbytes + 255) & ~(size_t)255;
        return p;
    };
    unsigned short* trunkB  = (unsigned short*)alloc(BIG * 2);   // bf16 trunk (only copy)
    unsigned short* bufQ    = (unsigned short*)alloc(BIG * 2);   // q -> h ; (xT low)
    unsigned short* bufK    = (unsigned short*)alloc(BIG * 2);   // k ; Qc  ; (xT high)
    unsigned short* bufV    = (unsigned short*)alloc(BIG * 2);   // v ; o_c
    float* scores  = (float*)alloc((size_t)BBATCH * NHEAD * NTOK * TTIME * 4);
    unsigned short* gpart = (unsigned short*)alloc((size_t)BBATCH * NSEG * NHEAD * NTOK * FMC * 2);
    float2* sstats = (float2*)alloc((size_t)BBATCH * NSEG * NHEAD * NTOK * 8);
    float* G       = (float*)alloc((size_t)BBATCH * NHEAD * NTOK * FMC * 4);
    float* qtok    = (float*)alloc((size_t)NTOK * FMC * 4);
    float* Osum    = (float*)alloc((size_t)BBATCH * NTOK * FMC * 4);
    float* summ5   = (float*)alloc((size_t)BBATCH * NTOK * FMC * 4);
    float* kvh     = (float*)alloc((size_t)BBATCH * NTOK * 1024 * 4);
    unsigned short* Wc   = (unsigned short*)alloc((size_t)FMC * DIMX * 2);
    unsigned short* Wcat = (unsigned short*)alloc((size_t)NLAYERS * WROWS * FMC * 2);
    unsigned short* Wblk = (unsigned short*)alloc((size_t)NLAYERS * FMC * FMC * 2);
    unsigned short* Wqca = (unsigned short*)alloc((size_t)FMC * FMC * 2);
    unsigned short* Wcao = (unsigned short*)alloc((size_t)FMC * FMC * 2);
    unsigned short* Wcow = (unsigned short*)alloc((size_t)NCC * FMC * 2);
    unsigned short* qkh  = (unsigned short*)alloc((size_t)NHEAD * NTOK * FMC * 2);
    unsigned short* xT = bufQ;  // spans bufQ+bufK (contiguous), dead after conv

    const Outs3 no3 = {};

    // --- weight conversion / precompute ---
    {
        const int n0 = FMC * DIMX, n1 = FMC * FMC, n2 = FMC * FMC,
                  n3 = NCC * FMC, n4 = NLAYERS * FMC * FMC;
        const int total = n0 + n1 + n2 + n3 + n4;
        hipLaunchKernelGGL(to_bf16_multi, dim3((total + 255) / 256), dim3(256), 0, stream,
                           cw1, Wc, n0, ca_in_w, Wqca, n1, ca_out_w, Wcao, n2,
                           cow, Wcow, n3, blk_w, Wblk, n4);
    }
    // qtok = tokens @ wq^T + bq   (rows = 10)
    hipLaunchKernelGGL(fast_proj, dim3(FMC / 4, NTOK), dim3(256), 0, stream,
                       tokens, sm_in_w, sm_in_b, qtok, FMC, 1.0f, 1.0f);
    hipLaunchKernelGGL(qkh_build, dim3(NHEAD * NTOK), dim3(256), 0, stream, qtok, sm_in_w, qkh);
    hipLaunchKernelGGL(build_wcat, dim3(2048), dim3(256), 0, stream, dal_q, dal_k, dal_v, qkh, Wcat);

    // --- input transpose + conv ---
    hipLaunchKernelGGL(transpose_x, dim3(TTIME / 64, DIMX / 64, BBATCH), dim3(256), 0, stream, x, xT);
    hipLaunchKernelGGL((gemm_mfma<16,1,0,0,0,0>), dim3(TTIME / 128, FMC / 128, BBATCH), dim3(256), 0, stream,
                       Wc, xT, FMC, cb1, nullptr, nullptr, trunkB, nullptr, no3);

    for (int i = 0; i < NLAYERS; ++i) {
        const int dil = 1 << i;
        // fused projections + summary scores: {q,k,v,scores} = Wcat[i] @ trunk
        Outs3 o3; o3.p[0] = bufQ; o3.p[1] = bufK; o3.p[2] = bufV;
        hipLaunchKernelGGL((gemm_mfma<8,0,0,0,2,0>), dim3(TTIME / 128, WROWS / 128, BBATCH), dim3(256), 0, stream,
                           Wcat + (size_t)i * WROWS * FMC, trunkB, 3 * FMC + NHEAD * NTOK,
                           nullptr, nullptr, nullptr, nullptr, scores, o3);
        // summary path: online-softmax partial accumulation, combine + layer-accumulate
        hipLaunchKernelGGL(g_accum_part, dim3(NSEG, BBATCH), dim3(256), 0, stream,
                           scores, trunkB, gpart, sstats);
        hipLaunchKernelGGL(g_reduce, dim3(FMC / 256, NHEAD * NTOK, BBATCH), dim3(256), 0, stream,
                           gpart, sstats, G, (i == 0) ? 1 : 0);
        // dilated attention (h aliases q in bufQ)
        hipLaunchKernelGGL(dal_elem_cl, dim3((unsigned)(BIG / 256 / 8)), dim3(256), 0, stream,
                           bufQ, bufK, bufV, rel_t + (size_t)i * FMC * 3, bufQ, dil);
        // trunk = (trunk + blk_w @ h + blk_b) * mask   (in-place bf16 resid)
        hipLaunchKernelGGL((gemm_mfma<8,1,1,1,0,0>), dim3(TTIME / 128, FMC / 128, BBATCH), dim3(256), 0, stream,
                           Wblk + (size_t)i * FMC * FMC, bufQ, FMC,
                           blk_b + (size_t)i * FMC, trunkB, mask, trunkB, nullptr, no3);
    }

    // --- deferred summary (linear): O = Wv@G + 5bv ; summ5 = sm_out(O)/5 ; kvh ---
    hipLaunchKernelGGL(fast_sm_ov, dim3(FMC / 4, BBATCH * NTOK), dim3(256), 0, stream,
                       G, sm_in_w, sm_in_b, Osum);
    hipLaunchKernelGGL(fast_proj, dim3(FMC / 4, BBATCH * NTOK), dim3(256), 0, stream,
                       Osum, sm_out_w, sm_out_b, summ5, FMC, 0.2f, 1.0f);
    hipLaunchKernelGGL(fast_proj, dim3(1024 / 4, BBATCH * NTOK), dim3(256), 0, stream,
                       summ5, ca_in_w + (size_t)FMC * FMC, nullptr, kvh, 1024, 1.0f, 0.0f);

    // --- final cross attention ---
    hipLaunchKernelGGL((gemm_mfma<8,0,0,0,0,0>), dim3(TTIME / 128, FMC / 128, BBATCH), dim3(256), 0, stream,
                       Wqca, trunkB, FMC, nullptr, nullptr, nullptr, bufK, nullptr, no3);
    hipLaunchKernelGGL(ca_fused_t, dim3(TTIME / 256, NHEAD, BBATCH), dim3(256), 0, stream,
                       bufK, kvh, bufV);
    // trunk += ca_out_w @ o_c   (in-place bf16 resid)
    hipLaunchKernelGGL((gemm_mfma<8,0,1,0,0,0>), dim3(TTIME / 128, FMC / 128, BBATCH), dim3(256), 0, stream,
                       Wcao, bufV, FMC, nullptr, trunkB, nullptr, trunkB, nullptr, no3);
    // d_out = (cow @ trunk + cob) * mask   (channel-major fp32)
    hipLaunchKernelGGL((gemm_mfma<8,1,0,1,0,1>), dim3(TTIME / 128, 2, BBATCH), dim3(256), 0, stream,
                       Wcow, trunkB, NCC, cob, nullptr, mask, nullptr, (float*)d_out, no3);
}

// Round 10
// 1296.350 us; speedup vs baseline: 1.2410x; 1.0092x over previous
//
#include <hip/hip_runtime.h>
#include <math.h>

#define FMC   512
#define DIMX  1024
#define NCC   157
#define NTOK  10
#define NHEAD 4
#define BBATCH 8
#define TTIME 4096
#define NLAYERS 5
#define NSEG  64
#define WROWS 1664   // 3*512 dal qkv + 40 qkh + 88 zero pad

typedef short bf16x8 __attribute__((ext_vector_type(8)));
typedef float f32x4v __attribute__((ext_vector_type(4)));
typedef unsigned short u16x8 __attribute__((ext_vector_type(8)));
typedef unsigned short u16x4 __attribute__((ext_vector_type(4)));

__device__ __forceinline__ float b2f(unsigned short u){
    union { unsigned int i; float f; } v; v.i = ((unsigned int)u) << 16; return v.f;
}
__device__ __forceinline__ unsigned short f2b(float f){
    union { float f; unsigned int i; } v; v.f = f;
    unsigned int r = v.i + 0x7FFFu + ((v.i >> 16) & 1u);
    return (unsigned short)(r >> 16);
}

struct Outs3 { unsigned short* p[3]; };

// ---------------------------------------------------------------------------
// MFMA GEMM: C[b,t,m] = sum_k W[m,k] * X[b,t,k]   (bf16 in, fp32 acc)
// Block 128m x 128t, BK=64, 4 waves (2x2). Reg-staged T14 pipeline (round-7
// verified) + coalesced LDS-transpose epilogue (round-9 verified).
// ---------------------------------------------------------------------------
template<int KSTEPS,int HAS_BIAS,int HAS_RESID,int HAS_MASK,int SPLIT,int CMAJOR>
__global__ __launch_bounds__(256) void gemm_mfma(
    const unsigned short* __restrict__ W, const unsigned short* __restrict__ X,
    int M,
    const float* __restrict__ bias, const unsigned short* __restrict__ residB,
    const float* __restrict__ mask,
    unsigned short* __restrict__ outB, float* __restrict__ outCM, Outs3 outs)
{
    constexpr int K = KSTEPS * 64;
    __shared__ __align__(16) unsigned short sh[2 * 128 * 64];  // As | Xs ; reused as C-tile
    unsigned short* As = sh;
    unsigned short* Xs = sh + 128 * 64;

    const int tid  = threadIdx.x;
    const int b    = blockIdx.z;
    const int m0   = blockIdx.y * 128;
    const int t0   = blockIdx.x * 128;
    const int wid  = tid >> 6, lane = tid & 63;
    const int wm   = (wid >> 1) * 64;
    const int wt   = (wid & 1) * 64;
    const int lanerow = lane & 15, laneoct = lane >> 4;

    int ldsOff[4];
    const unsigned short* gW[4];
    const unsigned short* gX[4];
    #pragma unroll
    for (int it = 0; it < 4; ++it) {
        const int idx = it * 256 + tid;
        const int row = idx >> 3, c16 = idx & 7;
        ldsOff[it] = row * 64 + ((c16 * 8) ^ ((row & 7) * 8));
        const int arow = CMAJOR ? min(m0 + row, M - 1) : (m0 + row);
        gW[it] = W + (size_t)arow * K + c16 * 8;
        gX[it] = X + ((size_t)(b * TTIME) + t0 + row) * K + c16 * 8;
    }

    f32x4v acc[4][4];
    #pragma unroll
    for (int i = 0; i < 4; ++i)
        #pragma unroll
        for (int j = 0; j < 4; ++j) { acc[i][j][0]=0.f; acc[i][j][1]=0.f; acc[i][j][2]=0.f; acc[i][j][3]=0.f; }

    u16x8 ra[4], rx[4];
    #pragma unroll
    for (int it = 0; it < 4; ++it) {
        ra[it] = *(const u16x8*)gW[it];
        rx[it] = *(const u16x8*)gX[it];
    }

    #pragma unroll
    for (int ks = 0; ks < KSTEPS; ++ks) {
        #pragma unroll
        for (int it = 0; it < 4; ++it) {
            *(u16x8*)&As[ldsOff[it]] = ra[it];
            *(u16x8*)&Xs[ldsOff[it]] = rx[it];
        }
        __syncthreads();
        if (ks + 1 < KSTEPS) {
            const int koff = (ks + 1) * 64;
            #pragma unroll
            for (int it = 0; it < 4; ++it) {
                ra[it] = *(const u16x8*)(gW[it] + koff);
                rx[it] = *(const u16x8*)(gX[it] + koff);
            }
        }
        #pragma unroll
        for (int ksub = 0; ksub < 2; ++ksub) {
            const int xk = (ksub * 32 + laneoct * 8) ^ ((lanerow & 7) * 8);
            bf16x8 af[4], bfr[4];
            #pragma unroll
            for (int m = 0; m < 4; ++m)
                af[m] = *(const bf16x8*)&As[(wm + m * 16 + lanerow) * 64 + xk];
            #pragma unroll
            for (int n = 0; n < 4; ++n)
                bfr[n] = *(const bf16x8*)&Xs[(wt + n * 16 + lanerow) * 64 + xk];
            #pragma unroll
            for (int m = 0; m < 4; ++m)
                #pragma unroll
                for (int n = 0; n < 4; ++n)
                    acc[m][n] = __builtin_amdgcn_mfma_f32_16x16x32_bf16(af[m], bfr[n], acc[m][n], 0, 0, 0);
        }
        __syncthreads();
    }

    // ---------------- epilogue ----------------
    if (CMAJOR || (SPLIT == 2 && m0 >= 3 * FMC)) {
        #pragma unroll
        for (int msub = 0; msub < 4; ++msub) {
            const int mq = m0 + wm + msub * 16 + laneoct * 4;
            float b0 = 0.f, b1 = 0.f, b2 = 0.f, b3 = 0.f;
            if (HAS_BIAS && CMAJOR) {
                b0 = (mq + 0 < M) ? bias[mq + 0] : 0.f;
                b1 = (mq + 1 < M) ? bias[mq + 1] : 0.f;
                b2 = (mq + 2 < M) ? bias[mq + 2] : 0.f;
                b3 = (mq + 3 < M) ? bias[mq + 3] : 0.f;
            }
            #pragma unroll
            for (int tsub = 0; tsub < 4; ++tsub) {
                const int t = t0 + wt + tsub * 16 + lanerow;
                float v0 = acc[msub][tsub][0] + b0;
                float v1 = acc[msub][tsub][1] + b1;
                float v2 = acc[msub][tsub][2] + b2;
                float v3 = acc[msub][tsub][3] + b3;
                if (HAS_MASK) {
                    const float mv = mask[b * TTIME + t];
                    v0 *= mv; v1 *= mv; v2 *= mv; v3 *= mv;
                }
                if (CMAJOR) {
                    if (mq + 0 < M) outCM[((size_t)(b * M + mq + 0)) * TTIME + t] = v0;
                    if (mq + 1 < M) outCM[((size_t)(b * M + mq + 1)) * TTIME + t] = v1;
                    if (mq + 2 < M) outCM[((size_t)(b * M + mq + 2)) * TTIME + t] = v2;
                    if (mq + 3 < M) outCM[((size_t)(b * M + mq + 3)) * TTIME + t] = v3;
                } else {
                    if (mq < 3 * FMC + NHEAD * NTOK) {
                        const int hl = mq - 3 * FMC;
                        float* sp = outCM + ((size_t)(b * NHEAD * NTOK + hl)) * TTIME + t;
                        sp[0] = v0; sp[TTIME] = v1; sp[2 * TTIME] = v2; sp[3 * TTIME] = v3;
                    }
                }
            }
        }
    } else {
        unsigned short* tile = sh;
        #pragma unroll
        for (int msub = 0; msub < 4; ++msub) {
            const int mq = m0 + wm + msub * 16 + laneoct * 4;
            float b0 = 0.f, b1 = 0.f, b2 = 0.f, b3 = 0.f;
            if (HAS_BIAS) {
                const float4 bq = *(const float4*)&bias[mq];
                b0 = bq.x; b1 = bq.y; b2 = bq.z; b3 = bq.w;
            }
            const int ml = wm + msub * 16 + laneoct * 4;
            #pragma unroll
            for (int tsub = 0; tsub < 4; ++tsub) {
                const int tl = wt + tsub * 16 + lanerow;
                const unsigned long long pk =
                    (unsigned long long)f2b(acc[msub][tsub][0] + b0) |
                    ((unsigned long long)f2b(acc[msub][tsub][1] + b1) << 16) |
                    ((unsigned long long)f2b(acc[msub][tsub][2] + b2) << 32) |
                    ((unsigned long long)f2b(acc[msub][tsub][3] + b3) << 48);
                *(unsigned long long*)&tile[tl * 128 + (ml ^ ((tl & 7) * 8))] = pk;
            }
        }
        __syncthreads();
        #pragma unroll
        for (int it = 0; it < 8; ++it) {
            const int ci = it * 256 + tid;
            const int tl = ci >> 4, mc = ci & 15;
            const int t = t0 + tl;
            u16x8 v = *(const u16x8*)&tile[tl * 128 + ((mc * 8) ^ ((tl & 7) * 8))];
            if (HAS_RESID || HAS_MASK) {
                const float mv = HAS_MASK ? mask[b * TTIME + t] : 1.0f;
                u16x8 rv;
                if (HAS_RESID)
                    rv = *(const u16x8*)(residB + ((size_t)(b * TTIME + t)) * FMC + m0 + mc * 8);
                u16x8 o;
                #pragma unroll
                for (int j = 0; j < 8; ++j) {
                    float f = b2f((unsigned short)v[j]);
                    if (HAS_RESID) f += b2f((unsigned short)rv[j]);
                    o[j] = (short)f2b(f * mv);
                }
                v = o;
            }
            unsigned short* dst;
            if (SPLIT == 2) {
                const int gm = m0 + mc * 8;
                dst = outs.p[gm >> 9] + ((size_t)(b * TTIME + t)) * FMC + (gm & 511);
            } else {
                dst = outB + ((size_t)(b * TTIME + t)) * FMC + m0 + mc * 8;
            }
            *(u16x8*)dst = v;
        }
    }
}

// ---------------------------------------------------------------------------
__global__ __launch_bounds__(256) void transpose_x(
    const float* __restrict__ x, unsigned short* __restrict__ xT)
{
    __shared__ float tile[64][65];
    const int b = blockIdx.z, d0 = blockIdx.y * 64, t0 = blockIdx.x * 64;
    const int tx = threadIdx.x & 63, ty = threadIdx.x >> 6;
    #pragma unroll
    for (int i = 0; i < 64; i += 4)
        tile[ty + i][tx] = x[((size_t)(b * DIMX + d0 + ty + i)) * TTIME + t0 + tx];
    __syncthreads();
    #pragma unroll
    for (int i = 0; i < 64; i += 4)
        xT[((size_t)(b * TTIME + t0 + ty + i)) * DIMX + d0 + tx] = f2b(tile[tx][ty + i]);
}

// fused 5-way f32 -> bf16 weight conversion (one launch)
__global__ __launch_bounds__(256) void to_bf16_multi(
    const float* __restrict__ s0, unsigned short* __restrict__ d0, int n0,
    const float* __restrict__ s1, unsigned short* __restrict__ d1, int n1,
    const float* __restrict__ s2, unsigned short* __restrict__ d2, int n2,
    const float* __restrict__ s3, unsigned short* __restrict__ d3, int n3,
    const float* __restrict__ s4, unsigned short* __restrict__ d4, int n4)
{
    int i = blockIdx.x * 256 + threadIdx.x;
    if (i < n0) { d0[i] = f2b(s0[i]); return; } i -= n0;
    if (i < n1) { d1[i] = f2b(s1[i]); return; } i -= n1;
    if (i < n2) { d2[i] = f2b(s2[i]); return; } i -= n2;
    if (i < n3) { d3[i] = f2b(s3[i]); return; } i -= n3;
    if (i < n4) { d4[i] = f2b(s4[i]); }
}

// Wcat rows: [0,512) dq, [512,1024) dk, [1024,1536) dv, [1536,1576) qkh, rest 0
__global__ void build_wcat(const float* __restrict__ dq, const float* __restrict__ dk,
                           const float* __restrict__ dv, const unsigned short* __restrict__ qkh,
                           unsigned short* __restrict__ Wcat)
{
    const int total = NLAYERS * WROWS * 512;
    for (int idx = blockIdx.x * 256 + threadIdx.x; idx < total; idx += gridDim.x * 256) {
        const int i = idx / (WROWS * 512);
        const int r = (idx >> 9) % WROWS;
        const int c = idx & 511;
        unsigned short v;
        if (r < 512)        v = f2b(dq[((size_t)i * 512 + r) * 512 + c]);
        else if (r < 1024)  v = f2b(dk[((size_t)i * 512 + (r - 512)) * 512 + c]);
        else if (r < 1536)  v = f2b(dv[((size_t)i * 512 + (r - 1024)) * 512 + c]);
        else if (r < 1576)  v = qkh[(r - 1536) * 512 + c];
        else                v = 0;
        Wcat[idx] = v;
    }
}

// qkh[(h*10+l)][c] = (1/sqrt(128)) * sum_d qtok[l][128h+d] * Wk[128h+d][c], bf16
__global__ __launch_bounds__(256) void qkh_build(
    const float* __restrict__ qtok, const float* __restrict__ sm_in_w,
    unsigned short* __restrict__ qkh)
{
    const int hl = blockIdx.x;
    const int h = hl / NTOK, l = hl % NTOK;
    __shared__ float q[128];
    if (threadIdx.x < 128) q[threadIdx.x] = qtok[l * FMC + h * 128 + threadIdx.x];
    __syncthreads();
    for (int c = threadIdx.x; c < FMC; c += 256) {
        float acc = 0.f;
        const float* wr = sm_in_w + (size_t)(FMC + h * 128) * FMC + c;
        #pragma unroll 4
        for (int d = 0; d < 128; ++d) acc += q[d] * wr[(size_t)d * FMC];
        qkh[hl * FMC + c] = f2b(acc * 0.08838834764831845f);
    }
}

// fast projection: out[r,e] = bias_scale*bias[e] + scale * sum_d in[r,d]*W[e,d]
__global__ __launch_bounds__(256) void fast_proj(
    const float* __restrict__ in, const float* __restrict__ W, const float* __restrict__ bias,
    float* __restrict__ out, int outStride, float scale, float bias_scale)
{
    const int r = blockIdx.y;
    const int w = threadIdx.x >> 6, lane = threadIdx.x & 63;
    const int e = blockIdx.x * 4 + w;
    const float4 a0 = *(const float4*)&in[(size_t)r * FMC + lane * 8];
    const float4 a1 = *(const float4*)&in[(size_t)r * FMC + lane * 8 + 4];
    const float4 w0 = *(const float4*)&W[(size_t)e * FMC + lane * 8];
    const float4 w1 = *(const float4*)&W[(size_t)e * FMC + lane * 8 + 4];
    float s = a0.x*w0.x + a0.y*w0.y + a0.z*w0.z + a0.w*w0.w
            + a1.x*w1.x + a1.y*w1.y + a1.z*w1.z + a1.w*w1.w;
    #pragma unroll
    for (int off = 32; off; off >>= 1) s += __shfl_xor(s, off);
    if (lane == 0)
        out[(size_t)r * outStride + e] = bias_scale * (bias ? bias[e] : 0.f) + scale * s;
}

// O[b,l,e] = 5*bv[e] + sum_c Wv[e,c] * G[b,h(e),l,c]    (deferred summary, Wv pass)
__global__ __launch_bounds__(256) void fast_sm_ov(
    const float* __restrict__ G, const float* __restrict__ sm_in_w,
    const float* __restrict__ sm_in_b, float* __restrict__ O)
{
    const int r = blockIdx.y;                 // b*NTOK + l
    const int b = r / NTOK, l = r % NTOK;
    const int w = threadIdx.x >> 6, lane = threadIdx.x & 63;
    const int e = blockIdx.x * 4 + w;
    const int h = e >> 7;
    const float* gin = G + (((size_t)(b * NHEAD + h)) * NTOK + l) * FMC;
    const float* wr  = sm_in_w + (size_t)(2 * FMC + e) * FMC;
    const float4 a0 = *(const float4*)&gin[lane * 8];
    const float4 a1 = *(const float4*)&gin[lane * 8 + 4];
    const float4 w0 = *(const float4*)&wr[lane * 8];
    const float4 w1 = *(const float4*)&wr[lane * 8 + 4];
    float s = a0.x*w0.x + a0.y*w0.y + a0.z*w0.z + a0.w*w0.w
            + a1.x*w1.x + a1.y*w1.y + a1.z*w1.z + a1.w*w1.w;
    #pragma unroll
    for (int off = 32; off; off >>= 1) s += __shfl_xor(s, off);
    if (lane == 0)
        O[(size_t)r * FMC + e] = 5.0f * sm_in_b[2 * FMC + e] + s;
}

// gpart[b][seg][h][l][c] = bf16( sum_{t in seg} exp(s - m_seg) * trunk[b,t,c] )
__global__ __launch_bounds__(256) void g_accum_part(
    const float* __restrict__ scores, const unsigned short* __restrict__ trunkB,
    unsigned short* __restrict__ gpart, float2* __restrict__ segstats)
{
    const int seg = blockIdx.x, b = blockIdx.y;
    const int h = threadIdx.x >> 6, lane = threadIdx.x & 63;
    const int c0 = lane * 8;
    const float* ap = scores + ((size_t)(b * NHEAD + h)) * NTOK * TTIME + seg * 64;
    float m_[NTOK];
    #pragma unroll
    for (int l = 0; l < NTOK; ++l) {
        float v = ap[(size_t)l * TTIME + lane];
        #pragma unroll
        for (int off = 32; off; off >>= 1) v = fmaxf(v, __shfl_xor(v, off));
        m_[l] = v;
    }
    float sum_[NTOK];
    float acc[NTOK][8];
    #pragma unroll
    for (int l = 0; l < NTOK; ++l) {
        sum_[l] = 0.f;
        #pragma unroll
        for (int j = 0; j < 8; ++j) acc[l][j] = 0.f;
    }
    const unsigned short* tp = trunkB + ((size_t)(b * TTIME) + seg * 64) * FMC + c0;
    #pragma unroll 2
    for (int tt = 0; tt < 64; ++tt) {
        const u16x8 tv = *(const u16x8*)(tp + (size_t)tt * FMC);
        float tf[8];
        #pragma unroll
        for (int j = 0; j < 8; ++j) tf[j] = b2f((unsigned short)tv[j]);
        #pragma unroll
        for (int l = 0; l < NTOK; ++l) {
            const float a = __expf(ap[(size_t)l * TTIME + tt] - m_[l]);
            sum_[l] += a;
            #pragma unroll
            for (int j = 0; j < 8; ++j) acc[l][j] += a * tf[j];
        }
    }
    unsigned short* gp = gpart + ((((size_t)(b * NSEG) + seg) * NHEAD + h) * NTOK) * FMC + c0;
    #pragma unroll
    for (int l = 0; l < NTOK; ++l) {
        u16x8 o;
        #pragma unroll
        for (int j = 0; j < 8; ++j) o[j] = (short)f2b(acc[l][j]);
        *(u16x8*)&gp[(size_t)l * FMC] = o;
    }
    if (lane == 0) {
        float2* st = segstats + (((size_t)(b * NSEG) + seg) * NHEAD + h) * NTOK;
        #pragma unroll
        for (int l = 0; l < NTOK; ++l) { float2 s; s.x = m_[l]; s.y = sum_[l]; st[l] = s; }
    }
}

// G[b][hl][c] (+)= softmax-normalized combine of bf16 gpart across segments.
__global__ __launch_bounds__(256) void g_reduce(
    const unsigned short* __restrict__ gpart, const float2* __restrict__ segstats,
    float* __restrict__ G, int first)
{
    const int tid = threadIdx.x;
    const int c = blockIdx.x * 256 + tid;
    const int hl = blockIdx.y;
    const int b = blockIdx.z;
    const int h = hl / NTOK, l = hl % NTOK;
    __shared__ float2 st[NSEG];
    if (tid < NSEG)
        st[tid] = segstats[(((size_t)(b * NSEG) + tid) * NHEAD + h) * NTOK + l];
    __syncthreads();
    float m = -1e30f;
    #pragma unroll 8
    for (int s = 0; s < NSEG; ++s) m = fmaxf(m, st[s].x);
    float denom = 0.f;
    #pragma unroll 8
    for (int s = 0; s < NSEG; ++s) denom += __expf(st[s].x - m) * st[s].y;
    const float invd = 1.0f / denom;
    const unsigned short* p = gpart + (((size_t)(b * NSEG) * NHEAD + h) * NTOK + l) * FMC + c;
    const size_t stride = (size_t)NHEAD * NTOK * FMC;
    float acc = 0.f;
    #pragma unroll 4
    for (int s = 0; s < NSEG; ++s) acc += __expf(st[s].x - m) * b2f(p[s * stride]);
    const float r = acc * invd;
    const size_t id = ((size_t)(b * NHEAD * NTOK) + hl) * FMC + c;
    G[id] = first ? r : (G[id] + r);
}

// dilated 3-tap attention, channel-last bf16; H may alias Q
__global__ __launch_bounds__(256) void dal_elem_cl(
    const unsigned short* __restrict__ Q, const unsigned short* __restrict__ K,
    const unsigned short* __restrict__ V, const float* __restrict__ rel,
    unsigned short* __restrict__ H, int dil)
{
    __shared__ float rels[FMC * 3];
    for (int i = threadIdx.x; i < FMC * 3; i += 256) rels[i] = rel[i];
    __syncthreads();
    const int g = blockIdx.x * 256 + threadIdx.x;
    const int c8 = g & 63;
    const int t = (g >> 6) & (TTIME - 1);
    const int b = g >> 18;
    const size_t base = ((size_t)(b * TTIME + t)) * FMC + c8 * 8;
    const u16x8 q8 = *(const u16x8*)(Q + base);
    const u16x8 k1 = *(const u16x8*)(K + base);
    const u16x8 v1 = *(const u16x8*)(V + base);
    u16x8 k0 = {0,0,0,0,0,0,0,0}, v0 = k0, k2 = k0, v2 = k0;
    const bool in0 = (t - dil) >= 0, in2 = (t + dil) < TTIME;
    if (in0) { k0 = *(const u16x8*)(K + base - (size_t)dil * FMC); v0 = *(const u16x8*)(V + base - (size_t)dil * FMC); }
    if (in2) { k2 = *(const u16x8*)(K + base + (size_t)dil * FMC); v2 = *(const u16x8*)(V + base + (size_t)dil * FMC); }
    u16x8 out;
    #pragma unroll
    for (int j = 0; j < 8; ++j) {
        const int c = c8 * 8 + j;
        const float q = b2f((unsigned short)q8[j]);
        const float kk0 = b2f((unsigned short)k0[j]);
        const float kk1 = b2f((unsigned short)k1[j]);
        const float kk2 = b2f((unsigned short)k2[j]);
        const float vv0 = b2f((unsigned short)v0[j]) + rels[c * 3 + 0];
        const float vv1 = b2f((unsigned short)v1[j]) + rels[c * 3 + 1];
        const float vv2 = b2f((unsigned short)v2[j]) + rels[c * 3 + 2];
        const float s0 = q * kk0, s1 = q * kk1, s2 = q * kk2;
        const float m = fmaxf(s0, fmaxf(s1, s2));
        const float e0 = __expf(s0 - m), e1 = __expf(s1 - m), e2 = __expf(s2 - m);
        const float hres = (e0 * vv0 + e1 * vv1 + e2 * vv2) / (e0 + e1 + e2);
        out[j] = (short)f2b(fmaxf(hres, 0.f));
    }
    *(u16x8*)(H + base) = out;
}

// ---------------------------------------------------------------------------
// final cross attention v2 — coalesced. Block = 64 t's x all 512 channels.
// Phase 1: (t,h) thread computes 10 scores + softmax -> s_lds.
// Phase 2: wave owns one t; lanes cover the 64 8-channel chunks ->
//          conflict-free ds_read_b128 of vh + 1KB-contiguous global store.
// kvh layout [b*NTOK+l][1024]: [0,512) = kh, [512,1024) = vh
// ---------------------------------------------------------------------------
__global__ __launch_bounds__(256) void ca_fused_v2(
    const unsigned short* __restrict__ Qc, const float* __restrict__ kvh,
    unsigned short* __restrict__ o_c)
{
    const int b = blockIdx.y, t0 = blockIdx.x * 64;
    __shared__ float kh_s[NTOK][512];
    __shared__ __align__(16) unsigned short vh_s[NTOK][512];
    __shared__ float s_lds[64][NHEAD * NTOK];
    for (int i = threadIdx.x; i < NTOK * 512; i += 256) {
        const int l = i >> 9, c = i & 511;
        kh_s[l][c] = kvh[((size_t)(b * NTOK) + l) * 1024 + c];
        vh_s[l][c] = f2b(kvh[((size_t)(b * NTOK) + l) * 1024 + 512 + c]);
    }
    __syncthreads();

    // phase 1: scores + softmax for (t = tid>>2, h = tid&3)
    {
        const int h = threadIdx.x & 3, tt = threadIdx.x >> 2;
        const unsigned short* qp = Qc + ((size_t)(b * TTIME) + t0 + tt) * FMC + h * 128;
        float s[NTOK];
        #pragma unroll
        for (int l = 0; l < NTOK; ++l) s[l] = 0.f;
        #pragma unroll
        for (int d0 = 0; d0 < 128; d0 += 8) {
            const u16x8 qv = *(const u16x8*)(qp + d0);
            float qf[8];
            #pragma unroll
            for (int j = 0; j < 8; ++j) qf[j] = b2f((unsigned short)qv[j]);
            #pragma unroll
            for (int l = 0; l < NTOK; ++l) {
                float a = 0.f;
                #pragma unroll
                for (int j = 0; j < 8; ++j) a += qf[j] * kh_s[l][h * 128 + d0 + j];
                s[l] += a;
            }
        }
        float mx = -1e30f;
        #pragma unroll
        for (int l = 0; l < NTOK; ++l) { s[l] *= 0.08838834764831845f; mx = fmaxf(mx, s[l]); }
        float sum = 0.f;
        #pragma unroll
        for (int l = 0; l < NTOK; ++l) { s[l] = __expf(s[l] - mx); sum += s[l]; }
        const float inv = 1.0f / sum;
        #pragma unroll
        for (int l = 0; l < NTOK; ++l) s_lds[tt][h * NTOK + l] = s[l] * inv;
    }
    __syncthreads();

    // phase 2: wave w at iter it handles t = it*4 + (tid>>6); lane = chunk
    const int lane = threadIdx.x & 63, w = threadIdx.x >> 6;
    const int hh = lane >> 4;
    #pragma unroll
    for (int it = 0; it < 16; ++it) {
        const int tl = it * 4 + w;
        float sv[NTOK];
        #pragma unroll
        for (int l = 0; l < NTOK; ++l) sv[l] = s_lds[tl][hh * NTOK + l];
        float of[8];
        #pragma unroll
        for (int j = 0; j < 8; ++j) of[j] = 0.f;
        #pragma unroll
        for (int l = 0; l < NTOK; ++l) {
            const u16x8 vv = *(const u16x8*)&vh_s[l][lane * 8];
            #pragma unroll
            for (int j = 0; j < 8; ++j) of[j] += sv[l] * b2f((unsigned short)vv[j]);
        }
        u16x8 o8;
        #pragma unroll
        for (int j = 0; j < 8; ++j) o8[j] = (short)f2b(of[j]);
        *(u16x8*)(o_c + ((size_t)(b * TTIME) + t0 + tl) * FMC + lane * 8) = o8;
    }
}

// ---------------------------------------------------------------------------
extern "C" void kernel_launch(void* const* d_in, const int* in_sizes, int n_in,
                              void* d_out, int out_size, void* d_ws, size_t ws_size,
                              hipStream_t stream)
{
    const float* x        = (const float*)d_in[0];
    const float* mask     = (const float*)d_in[1];
    const float* cw1      = (const float*)d_in[2];
    const float* cb1      = (const float*)d_in[3];
    const float* dal_q    = (const float*)d_in[4];
    const float* dal_k    = (const float*)d_in[5];
    const float* dal_v    = (const float*)d_in[6];
    const float* rel_t    = (const float*)d_in[7];
    const float* blk_w    = (const float*)d_in[8];
    const float* blk_b    = (const float*)d_in[9];
    const float* cow      = (const float*)d_in[10];
    const float* cob      = (const float*)d_in[11];
    const float* tokens   = (const float*)d_in[12];
    const float* sm_in_w  = (const float*)d_in[13];
    const float* sm_in_b  = (const float*)d_in[14];
    const float* sm_out_w = (const float*)d_in[15];
    const float* sm_out_b = (const float*)d_in[16];
    const float* ca_in_w  = (const float*)d_in[17];
    const float* ca_out_w = (const float*)d_in[18];
    (void)in_sizes; (void)n_in; (void)out_size; (void)ws_size;

    const size_t BIG = (size_t)BBATCH * FMC * TTIME;   // 16.7M elems
    char* ws = (char*)d_ws;
    size_t off = 0;
    auto alloc = [&](size_t nbytes) {
        void* p = (void*)(ws + off);
        off = (off + nbytes + 255) & ~(size_t)255;
        return p;
    };
    unsigned short* trunkB  = (unsigned short*)alloc(BIG * 2);   // bf16 trunk (only copy)
    unsigned short* bufQ    = (unsigned short*)alloc(BIG * 2);   // q -> h ; (xT low)
    unsigned short* bufK    = (unsigned short*)alloc(BIG * 2);   // k ; Qc  ; (xT high)
    unsigned short* bufV    = (unsigned short*)alloc(BIG * 2);   // v ; o_c
    float* scores  = (float*)alloc((size_t)BBATCH * NHEAD * NTOK * TTIME * 4);
    unsigned short* gpart = (unsigned short*)alloc((size_t)BBATCH * NSEG * NHEAD * NTOK * FMC * 2);
    float2* sstats = (float2*)alloc((size_t)BBATCH * NSEG * NHEAD * NTOK * 8);
    float* G       = (float*)alloc((size_t)BBATCH * NHEAD * NTOK * FMC * 4);
    float* qtok    = (float*)alloc((size_t)NTOK * FMC * 4);
    float* Osum    = (float*)alloc((size_t)BBATCH * NTOK * FMC * 4);
    float* summ5   = (float*)alloc((size_t)BBATCH * NTOK * FMC * 4);
    float* kvh     = (float*)alloc((size_t)BBATCH * NTOK * 1024 * 4);
    unsigned short* Wc   = (unsigned short*)alloc((size_t)FMC * DIMX * 2);
    unsigned short* Wcat = (unsigned short*)alloc((size_t)NLAYERS * WROWS * FMC * 2);
    unsigned short* Wblk = (unsigned short*)alloc((size_t)NLAYERS * FMC * FMC * 2);
    unsigned short* Wqca = (unsigned short*)alloc((size_t)FMC * FMC * 2);
    unsigned short* Wcao = (unsigned short*)alloc((size_t)FMC * FMC * 2);
    unsigned short* Wcow = (unsigned short*)alloc((size_t)NCC * FMC * 2);
    unsigned short* qkh  = (unsigned short*)alloc((size_t)NHEAD * NTOK * FMC * 2);
    unsigned short* xT = bufQ;  // spans bufQ+bufK (contiguous), dead after conv

    const Outs3 no3 = {};

    // --- weight conversion / precompute ---
    {
        const int n0 = FMC * DIMX, n1 = FMC * FMC, n2 = FMC * FMC,
                  n3 = NCC * FMC, n4 = NLAYERS * FMC * FMC;
        const int total = n0 + n1 + n2 + n3 + n4;
        hipLaunchKernelGGL(to_bf16_multi, dim3((total + 255) / 256), dim3(256), 0, stream,
                           cw1, Wc, n0, ca_in_w, Wqca, n1, ca_out_w, Wcao, n2,
                           cow, Wcow, n3, blk_w, Wblk, n4);
    }
    // qtok = tokens @ wq^T + bq   (rows = 10)
    hipLaunchKernelGGL(fast_proj, dim3(FMC / 4, NTOK), dim3(256), 0, stream,
                       tokens, sm_in_w, sm_in_b, qtok, FMC, 1.0f, 1.0f);
    hipLaunchKernelGGL(qkh_build, dim3(NHEAD * NTOK), dim3(256), 0, stream, qtok, sm_in_w, qkh);
    hipLaunchKernelGGL(build_wcat, dim3(2048), dim3(256), 0, stream, dal_q, dal_k, dal_v, qkh, Wcat);

    // --- input transpose + conv ---
    hipLaunchKernelGGL(transpose_x, dim3(TTIME / 64, DIMX / 64, BBATCH), dim3(256), 0, stream, x, xT);
    hipLaunchKernelGGL((gemm_mfma<16,1,0,0,0,0>), dim3(TTIME / 128, FMC / 128, BBATCH), dim3(256), 0, stream,
                       Wc, xT, FMC, cb1, nullptr, nullptr, trunkB, nullptr, no3);

    for (int i = 0; i < NLAYERS; ++i) {
        const int dil = 1 << i;
        // fused projections + summary scores: {q,k,v,scores} = Wcat[i] @ trunk
        Outs3 o3; o3.p[0] = bufQ; o3.p[1] = bufK; o3.p[2] = bufV;
        hipLaunchKernelGGL((gemm_mfma<8,0,0,0,2,0>), dim3(TTIME / 128, WROWS / 128, BBATCH), dim3(256), 0, stream,
                           Wcat + (size_t)i * WROWS * FMC, trunkB, 3 * FMC + NHEAD * NTOK,
                           nullptr, nullptr, nullptr, nullptr, scores, o3);
        // summary path: online-softmax partial accumulation, combine + layer-accumulate
        hipLaunchKernelGGL(g_accum_part, dim3(NSEG, BBATCH), dim3(256), 0, stream,
                           scores, trunkB, gpart, sstats);
        hipLaunchKernelGGL(g_reduce, dim3(FMC / 256, NHEAD * NTOK, BBATCH), dim3(256), 0, stream,
                           gpart, sstats, G, (i == 0) ? 1 : 0);
        // dilated attention (h aliases q in bufQ)
        hipLaunchKernelGGL(dal_elem_cl, dim3((unsigned)(BIG / 256 / 8)), dim3(256), 0, stream,
                           bufQ, bufK, bufV, rel_t + (size_t)i * FMC * 3, bufQ, dil);
        // trunk = (trunk + blk_w @ h + blk_b) * mask   (in-place bf16 resid)
        hipLaunchKernelGGL((gemm_mfma<8,1,1,1,0,0>), dim3(TTIME / 128, FMC / 128, BBATCH), dim3(256), 0, stream,
                           Wblk + (size_t)i * FMC * FMC, bufQ, FMC,
                           blk_b + (size_t)i * FMC, trunkB, mask, trunkB, nullptr, no3);
    }

    // --- deferred summary (linear): O = Wv@G + 5bv ; summ5 = sm_out(O)/5 ; kvh ---
    hipLaunchKernelGGL(fast_sm_ov, dim3(FMC / 4, BBATCH * NTOK), dim3(256), 0, stream,
                       G, sm_in_w, sm_in_b, Osum);
    hipLaunchKernelGGL(fast_proj, dim3(FMC / 4, BBATCH * NTOK), dim3(256), 0, stream,
                       Osum, sm_out_w, sm_out_b, summ5, FMC, 0.2f, 1.0f);
    hipLaunchKernelGGL(fast_proj, dim3(1024 / 4, BBATCH * NTOK), dim3(256), 0, stream,
                       summ5, ca_in_w + (size_t)FMC * FMC, nullptr, kvh, 1024, 1.0f, 0.0f);

    // --- final cross attention ---
    hipLaunchKernelGGL((gemm_mfma<8,0,0,0,0,0>), dim3(TTIME / 128, FMC / 128, BBATCH), dim3(256), 0, stream,
                       Wqca, trunkB, FMC, nullptr, nullptr, nullptr, bufK, nullptr, no3);
    hipLaunchKernelGGL(ca_fused_v2, dim3(TTIME / 64, BBATCH), dim3(256), 0, stream,
                       bufK, kvh, bufV);
    // trunk += ca_out_w @ o_c   (in-place bf16 resid)
    hipLaunchKernelGGL((gemm_mfma<8,0,1,0,0,0>), dim3(TTIME / 128, FMC / 128, BBATCH), dim3(256), 0, stream,
                       Wcao, bufV, FMC, nullptr, trunkB, nullptr, trunkB, nullptr, no3);
    // d_out = (cow @ trunk + cob) * mask   (channel-major fp32)
    hipLaunchKernelGGL((gemm_mfma<8,1,0,1,0,1>), dim3(TTIME / 128, 2, BBATCH), dim3(256), 0, stream,
                       Wcow, trunkB, NCC, cob, nullptr, mask, nullptr, (float*)d_out, no3);
}

// Round 11
// 1284.859 us; speedup vs baseline: 1.2521x; 1.0089x over previous
//
#include <hip/hip_runtime.h>
#include <math.h>

#define FMC   512
#define DIMX  1024
#define NCC   157
#define NTOK  10
#define NHEAD 4
#define BBATCH 8
#define TTIME 4096
#define NLAYERS 5
#define NSEG  64
#define WROWS 1664   // 3*512 dal qkv + 40 qkh + 88 zero pad

typedef short bf16x8 __attribute__((ext_vector_type(8)));
typedef float f32x4v __attribute__((ext_vector_type(4)));
typedef unsigned short u16x8 __attribute__((ext_vector_type(8)));
typedef unsigned short u16x4 __attribute__((ext_vector_type(4)));

__device__ __forceinline__ float b2f(unsigned short u){
    union { unsigned int i; float f; } v; v.i = ((unsigned int)u) << 16; return v.f;
}
__device__ __forceinline__ unsigned short f2b(float f){
    union { float f; unsigned int i; } v; v.f = f;
    unsigned int r = v.i + 0x7FFFu + ((v.i >> 16) & 1u);
    return (unsigned short)(r >> 16);
}

struct Outs3 { unsigned short* p[3]; };

// ---------------------------------------------------------------------------
// MFMA GEMM: C[b,t,m] = sum_k W[m,k] * X[b,t,k]   (bf16 in, fp32 acc)
// Block 128m x 128t, BK=64, 4 waves (2x2).
// PIPE=0: reg-staged T14 pipeline (round-7/9/10 verified), 32KB LDS.
// PIPE=1: global_load_lds double-buffer with COUNTED vmcnt + raw s_barrier
//   (T4): stage(next) -> vmcnt(8) [prev tile drained, this tile's 8 loads
//   stay in flight] -> barrier -> MFMA -> barrier. 64KB LDS, 2 blocks/CU.
//   ONLY safe when the kernel has no other global loads (no bias/resid/mask)
//   so the vmcnt arithmetic is exact.
// Coalesced LDS-transpose epilogue for bf16 outputs (round-9 verified).
// ---------------------------------------------------------------------------
template<int KSTEPS,int HAS_BIAS,int HAS_RESID,int HAS_MASK,int SPLIT,int CMAJOR,int PIPE>
__global__ __launch_bounds__(256) void gemm_mfma(
    const unsigned short* __restrict__ W, const unsigned short* __restrict__ X,
    int M,
    const float* __restrict__ bias, const unsigned short* __restrict__ residB,
    const float* __restrict__ mask,
    unsigned short* __restrict__ outB, float* __restrict__ outCM, Outs3 outs)
{
    constexpr int K = KSTEPS * 64;
    __shared__ __align__(16) unsigned short sh[(PIPE ? 4 : 2) * 128 * 64];

    const int tid  = threadIdx.x;
    const int b    = blockIdx.z;
    const int m0   = blockIdx.y * 128;
    const int t0   = blockIdx.x * 128;
    const int wid  = tid >> 6, lane = tid & 63;
    const int wm   = (wid >> 1) * 64;
    const int wt   = (wid & 1) * 64;
    const int lanerow = lane & 15, laneoct = lane >> 4;

    f32x4v acc[4][4];
    #pragma unroll
    for (int i = 0; i < 4; ++i)
        #pragma unroll
        for (int j = 0; j < 4; ++j) { acc[i][j][0]=0.f; acc[i][j][1]=0.f; acc[i][j][2]=0.f; acc[i][j][3]=0.f; }

    if constexpr (PIPE) {
        // ---- gload_lds double-buffered pipeline (counted vmcnt, raw barriers) ----
        // wave-uniform LDS segment base + per-lane inverse-swizzled SOURCE (rule 21)
        const unsigned short* pgA[4];
        const unsigned short* pgX[4];
        int pBase[4];
        #pragma unroll
        for (int i = 0; i < 4; ++i) {
            const int seg = i * 4 + wid;
            const int r0  = seg * 8;
            const int row = r0 + (lane >> 3);
            const int chs = (((lane & 7) ^ (row & 7)) * 8);
            pgA[i] = W + (size_t)(m0 + row) * K + chs;
            pgX[i] = X + ((size_t)(b * TTIME) + t0 + row) * K + chs;
            pBase[i] = r0 * 64;
        }
        auto stageP = [&](int buf, int ks) {
            const int koff = ks * 64;
            #pragma unroll
            for (int i = 0; i < 4; ++i) {
                __builtin_amdgcn_global_load_lds(
                    (const __attribute__((address_space(1))) void*)(pgA[i] + koff),
                    (__attribute__((address_space(3))) void*)&sh[buf * 8192 + pBase[i]], 16, 0, 0);
                __builtin_amdgcn_global_load_lds(
                    (const __attribute__((address_space(1))) void*)(pgX[i] + koff),
                    (__attribute__((address_space(3))) void*)&sh[16384 + buf * 8192 + pBase[i]], 16, 0, 0);
            }
        };
        stageP(0, 0);
        #pragma unroll
        for (int ks = 0; ks < KSTEPS; ++ks) {
            const int cur = ks & 1;
            if (ks + 1 < KSTEPS) {
                stageP(cur ^ 1, ks + 1);                      // 8 loads into other buffer
                asm volatile("s_waitcnt vmcnt(8)" ::: "memory");  // drain prev tile only
            } else {
                asm volatile("s_waitcnt vmcnt(0)" ::: "memory");
            }
            asm volatile("s_barrier" ::: "memory");           // tile `cur` resident for all
            const unsigned short* Acur = sh + cur * 8192;
            const unsigned short* Xcur = sh + 16384 + cur * 8192;
            #pragma unroll
            for (int ksub = 0; ksub < 2; ++ksub) {
                const int xk = (ksub * 32 + laneoct * 8) ^ ((lanerow & 7) * 8);
                bf16x8 af[4], bfr[4];
                #pragma unroll
                for (int m = 0; m < 4; ++m)
                    af[m] = *(const bf16x8*)&Acur[(wm + m * 16 + lanerow) * 64 + xk];
                #pragma unroll
                for (int n = 0; n < 4; ++n)
                    bfr[n] = *(const bf16x8*)&Xcur[(wt + n * 16 + lanerow) * 64 + xk];
                #pragma unroll
                for (int m = 0; m < 4; ++m)
                    #pragma unroll
                    for (int n = 0; n < 4; ++n)
                        acc[m][n] = __builtin_amdgcn_mfma_f32_16x16x32_bf16(af[m], bfr[n], acc[m][n], 0, 0, 0);
            }
            asm volatile("s_barrier" ::: "memory");           // all reads of `cur` done
        }
    } else {
        // ---- reg-staged path (round-10, verified) ----
        unsigned short* As = sh;
        unsigned short* Xs = sh + 128 * 64;
        int ldsOff[4];
        const unsigned short* gW[4];
        const unsigned short* gX[4];
        #pragma unroll
        for (int it = 0; it < 4; ++it) {
            const int idx = it * 256 + tid;
            const int row = idx >> 3, c16 = idx & 7;
            ldsOff[it] = row * 64 + ((c16 * 8) ^ ((row & 7) * 8));
            const int arow = CMAJOR ? min(m0 + row, M - 1) : (m0 + row);
            gW[it] = W + (size_t)arow * K + c16 * 8;
            gX[it] = X + ((size_t)(b * TTIME) + t0 + row) * K + c16 * 8;
        }
        u16x8 ra[4], rx[4];
        #pragma unroll
        for (int it = 0; it < 4; ++it) {
            ra[it] = *(const u16x8*)gW[it];
            rx[it] = *(const u16x8*)gX[it];
        }
        #pragma unroll
        for (int ks = 0; ks < KSTEPS; ++ks) {
            #pragma unroll
            for (int it = 0; it < 4; ++it) {
                *(u16x8*)&As[ldsOff[it]] = ra[it];
                *(u16x8*)&Xs[ldsOff[it]] = rx[it];
            }
            __syncthreads();
            if (ks + 1 < KSTEPS) {
                const int koff = (ks + 1) * 64;
                #pragma unroll
                for (int it = 0; it < 4; ++it) {
                    ra[it] = *(const u16x8*)(gW[it] + koff);
                    rx[it] = *(const u16x8*)(gX[it] + koff);
                }
            }
            #pragma unroll
            for (int ksub = 0; ksub < 2; ++ksub) {
                const int xk = (ksub * 32 + laneoct * 8) ^ ((lanerow & 7) * 8);
                bf16x8 af[4], bfr[4];
                #pragma unroll
                for (int m = 0; m < 4; ++m)
                    af[m] = *(const bf16x8*)&As[(wm + m * 16 + lanerow) * 64 + xk];
                #pragma unroll
                for (int n = 0; n < 4; ++n)
                    bfr[n] = *(const bf16x8*)&Xs[(wt + n * 16 + lanerow) * 64 + xk];
                #pragma unroll
                for (int m = 0; m < 4; ++m)
                    #pragma unroll
                    for (int n = 0; n < 4; ++n)
                        acc[m][n] = __builtin_amdgcn_mfma_f32_16x16x32_bf16(af[m], bfr[n], acc[m][n], 0, 0, 0);
            }
            __syncthreads();
        }
    }

    // ---------------- epilogue ----------------
    if (CMAJOR || (SPLIT == 2 && m0 >= 3 * FMC)) {
        #pragma unroll
        for (int msub = 0; msub < 4; ++msub) {
            const int mq = m0 + wm + msub * 16 + laneoct * 4;
            float b0 = 0.f, b1 = 0.f, b2 = 0.f, b3 = 0.f;
            if (HAS_BIAS && CMAJOR) {
                b0 = (mq + 0 < M) ? bias[mq + 0] : 0.f;
                b1 = (mq + 1 < M) ? bias[mq + 1] : 0.f;
                b2 = (mq + 2 < M) ? bias[mq + 2] : 0.f;
                b3 = (mq + 3 < M) ? bias[mq + 3] : 0.f;
            }
            #pragma unroll
            for (int tsub = 0; tsub < 4; ++tsub) {
                const int t = t0 + wt + tsub * 16 + lanerow;
                float v0 = acc[msub][tsub][0] + b0;
                float v1 = acc[msub][tsub][1] + b1;
                float v2 = acc[msub][tsub][2] + b2;
                float v3 = acc[msub][tsub][3] + b3;
                if (HAS_MASK) {
                    const float mv = mask[b * TTIME + t];
                    v0 *= mv; v1 *= mv; v2 *= mv; v3 *= mv;
                }
                if (CMAJOR) {
                    if (mq + 0 < M) outCM[((size_t)(b * M + mq + 0)) * TTIME + t] = v0;
                    if (mq + 1 < M) outCM[((size_t)(b * M + mq + 1)) * TTIME + t] = v1;
                    if (mq + 2 < M) outCM[((size_t)(b * M + mq + 2)) * TTIME + t] = v2;
                    if (mq + 3 < M) outCM[((size_t)(b * M + mq + 3)) * TTIME + t] = v3;
                } else {
                    if (mq < 3 * FMC + NHEAD * NTOK) {
                        const int hl = mq - 3 * FMC;
                        float* sp = outCM + ((size_t)(b * NHEAD * NTOK + hl)) * TTIME + t;
                        sp[0] = v0; sp[TTIME] = v1; sp[2 * TTIME] = v2; sp[3 * TTIME] = v3;
                    }
                }
            }
        }
    } else {
        unsigned short* tile = sh;
        #pragma unroll
        for (int msub = 0; msub < 4; ++msub) {
            const int mq = m0 + wm + msub * 16 + laneoct * 4;
            float b0 = 0.f, b1 = 0.f, b2 = 0.f, b3 = 0.f;
            if (HAS_BIAS) {
                const float4 bq = *(const float4*)&bias[mq];
                b0 = bq.x; b1 = bq.y; b2 = bq.z; b3 = bq.w;
            }
            const int ml = wm + msub * 16 + laneoct * 4;
            #pragma unroll
            for (int tsub = 0; tsub < 4; ++tsub) {
                const int tl = wt + tsub * 16 + lanerow;
                const unsigned long long pk =
                    (unsigned long long)f2b(acc[msub][tsub][0] + b0) |
                    ((unsigned long long)f2b(acc[msub][tsub][1] + b1) << 16) |
                    ((unsigned long long)f2b(acc[msub][tsub][2] + b2) << 32) |
                    ((unsigned long long)f2b(acc[msub][tsub][3] + b3) << 48);
                *(unsigned long long*)&tile[tl * 128 + (ml ^ ((tl & 7) * 8))] = pk;
            }
        }
        __syncthreads();
        #pragma unroll
        for (int it = 0; it < 8; ++it) {
            const int ci = it * 256 + tid;
            const int tl = ci >> 4, mc = ci & 15;
            const int t = t0 + tl;
            u16x8 v = *(const u16x8*)&tile[tl * 128 + ((mc * 8) ^ ((tl & 7) * 8))];
            if (HAS_RESID || HAS_MASK) {
                const float mv = HAS_MASK ? mask[b * TTIME + t] : 1.0f;
                u16x8 rv;
                if (HAS_RESID)
                    rv = *(const u16x8*)(residB + ((size_t)(b * TTIME + t)) * FMC + m0 + mc * 8);
                u16x8 o;
                #pragma unroll
                for (int j = 0; j < 8; ++j) {
                    float f = b2f((unsigned short)v[j]);
                    if (HAS_RESID) f += b2f((unsigned short)rv[j]);
                    o[j] = (short)f2b(f * mv);
                }
                v = o;
            }
            unsigned short* dst;
            if (SPLIT == 2) {
                const int gm = m0 + mc * 8;
                dst = outs.p[gm >> 9] + ((size_t)(b * TTIME + t)) * FMC + (gm & 511);
            } else {
                dst = outB + ((size_t)(b * TTIME + t)) * FMC + m0 + mc * 8;
            }
            *(u16x8*)dst = v;
        }
    }
}

// ---------------------------------------------------------------------------
__global__ __launch_bounds__(256) void transpose_x(
    const float* __restrict__ x, unsigned short* __restrict__ xT)
{
    __shared__ float tile[64][65];
    const int b = blockIdx.z, d0 = blockIdx.y * 64, t0 = blockIdx.x * 64;
    const int tx = threadIdx.x & 63, ty = threadIdx.x >> 6;
    #pragma unroll
    for (int i = 0; i < 64; i += 4)
        tile[ty + i][tx] = x[((size_t)(b * DIMX + d0 + ty + i)) * TTIME + t0 + tx];
    __syncthreads();
    #pragma unroll
    for (int i = 0; i < 64; i += 4)
        xT[((size_t)(b * TTIME + t0 + ty + i)) * DIMX + d0 + tx] = f2b(tile[tx][ty + i]);
}

// fused 5-way f32 -> bf16 weight conversion (one launch)
__global__ __launch_bounds__(256) void to_bf16_multi(
    const float* __restrict__ s0, unsigned short* __restrict__ d0, int n0,
    const float* __restrict__ s1, unsigned short* __restrict__ d1, int n1,
    const float* __restrict__ s2, unsigned short* __restrict__ d2, int n2,
    const float* __restrict__ s3, unsigned short* __restrict__ d3, int n3,
    const float* __restrict__ s4, unsigned short* __restrict__ d4, int n4)
{
    int i = blockIdx.x * 256 + threadIdx.x;
    if (i < n0) { d0[i] = f2b(s0[i]); return; } i -= n0;
    if (i < n1) { d1[i] = f2b(s1[i]); return; } i -= n1;
    if (i < n2) { d2[i] = f2b(s2[i]); return; } i -= n2;
    if (i < n3) { d3[i] = f2b(s3[i]); return; } i -= n3;
    if (i < n4) { d4[i] = f2b(s4[i]); }
}

// Wcat rows: [0,512) dq, [512,1024) dk, [1024,1536) dv, [1536,1576) qkh, rest 0
__global__ void build_wcat(const float* __restrict__ dq, const float* __restrict__ dk,
                           const float* __restrict__ dv, const unsigned short* __restrict__ qkh,
                           unsigned short* __restrict__ Wcat)
{
    const int total = NLAYERS * WROWS * 512;
    for (int idx = blockIdx.x * 256 + threadIdx.x; idx < total; idx += gridDim.x * 256) {
        const int i = idx / (WROWS * 512);
        const int r = (idx >> 9) % WROWS;
        const int c = idx & 511;
        unsigned short v;
        if (r < 512)        v = f2b(dq[((size_t)i * 512 + r) * 512 + c]);
        else if (r < 1024)  v = f2b(dk[((size_t)i * 512 + (r - 512)) * 512 + c]);
        else if (r < 1536)  v = f2b(dv[((size_t)i * 512 + (r - 1024)) * 512 + c]);
        else if (r < 1576)  v = qkh[(r - 1536) * 512 + c];
        else                v = 0;
        Wcat[idx] = v;
    }
}

// qkh[(h*10+l)][c] = (1/sqrt(128)) * sum_d qtok[l][128h+d] * Wk[128h+d][c], bf16
__global__ __launch_bounds__(256) void qkh_build(
    const float* __restrict__ qtok, const float* __restrict__ sm_in_w,
    unsigned short* __restrict__ qkh)
{
    const int hl = blockIdx.x;
    const int h = hl / NTOK, l = hl % NTOK;
    __shared__ float q[128];
    if (threadIdx.x < 128) q[threadIdx.x] = qtok[l * FMC + h * 128 + threadIdx.x];
    __syncthreads();
    for (int c = threadIdx.x; c < FMC; c += 256) {
        float acc = 0.f;
        const float* wr = sm_in_w + (size_t)(FMC + h * 128) * FMC + c;
        #pragma unroll 4
        for (int d = 0; d < 128; ++d) acc += q[d] * wr[(size_t)d * FMC];
        qkh[hl * FMC + c] = f2b(acc * 0.08838834764831845f);
    }
}

// fast projection: out[r,e] = bias_scale*bias[e] + scale * sum_d in[r,d]*W[e,d]
__global__ __launch_bounds__(256) void fast_proj(
    const float* __restrict__ in, const float* __restrict__ W, const float* __restrict__ bias,
    float* __restrict__ out, int outStride, float scale, float bias_scale)
{
    const int r = blockIdx.y;
    const int w = threadIdx.x >> 6, lane = threadIdx.x & 63;
    const int e = blockIdx.x * 4 + w;
    const float4 a0 = *(const float4*)&in[(size_t)r * FMC + lane * 8];
    const float4 a1 = *(const float4*)&in[(size_t)r * FMC + lane * 8 + 4];
    const float4 w0 = *(const float4*)&W[(size_t)e * FMC + lane * 8];
    const float4 w1 = *(const float4*)&W[(size_t)e * FMC + lane * 8 + 4];
    float s = a0.x*w0.x + a0.y*w0.y + a0.z*w0.z + a0.w*w0.w
            + a1.x*w1.x + a1.y*w1.y + a1.z*w1.z + a1.w*w1.w;
    #pragma unroll
    for (int off = 32; off; off >>= 1) s += __shfl_xor(s, off);
    if (lane == 0)
        out[(size_t)r * outStride + e] = bias_scale * (bias ? bias[e] : 0.f) + scale * s;
}

// O[b,l,e] = 5*bv[e] + sum_c Wv[e,c] * G[b,h(e),l,c]    (deferred summary, Wv pass)
__global__ __launch_bounds__(256) void fast_sm_ov(
    const float* __restrict__ G, const float* __restrict__ sm_in_w,
    const float* __restrict__ sm_in_b, float* __restrict__ O)
{
    const int r = blockIdx.y;                 // b*NTOK + l
    const int b = r / NTOK, l = r % NTOK;
    const int w = threadIdx.x >> 6, lane = threadIdx.x & 63;
    const int e = blockIdx.x * 4 + w;
    const int h = e >> 7;
    const float* gin = G + (((size_t)(b * NHEAD + h)) * NTOK + l) * FMC;
    const float* wr  = sm_in_w + (size_t)(2 * FMC + e) * FMC;
    const float4 a0 = *(const float4*)&gin[lane * 8];
    const float4 a1 = *(const float4*)&gin[lane * 8 + 4];
    const float4 w0 = *(const float4*)&wr[lane * 8];
    const float4 w1 = *(const float4*)&wr[lane * 8 + 4];
    float s = a0.x*w0.x + a0.y*w0.y + a0.z*w0.z + a0.w*w0.w
            + a1.x*w1.x + a1.y*w1.y + a1.z*w1.z + a1.w*w1.w;
    #pragma unroll
    for (int off = 32; off; off >>= 1) s += __shfl_xor(s, off);
    if (lane == 0)
        O[(size_t)r * FMC + e] = 5.0f * sm_in_b[2 * FMC + e] + s;
}

// gpart[b][seg][h][l][c] = bf16( sum_{t in seg} exp(s - m_seg) * trunk[b,t,c] )
__global__ __launch_bounds__(256) void g_accum_part(
    const float* __restrict__ scores, const unsigned short* __restrict__ trunkB,
    unsigned short* __restrict__ gpart, float2* __restrict__ segstats)
{
    const int seg = blockIdx.x, b = blockIdx.y;
    const int h = threadIdx.x >> 6, lane = threadIdx.x & 63;
    const int c0 = lane * 8;
    const float* ap = scores + ((size_t)(b * NHEAD + h)) * NTOK * TTIME + seg * 64;
    float m_[NTOK];
    #pragma unroll
    for (int l = 0; l < NTOK; ++l) {
        float v = ap[(size_t)l * TTIME + lane];
        #pragma unroll
        for (int off = 32; off; off >>= 1) v = fmaxf(v, __shfl_xor(v, off));
        m_[l] = v;
    }
    float sum_[NTOK];
    float acc[NTOK][8];
    #pragma unroll
    for (int l = 0; l < NTOK; ++l) {
        sum_[l] = 0.f;
        #pragma unroll
        for (int j = 0; j < 8; ++j) acc[l][j] = 0.f;
    }
    const unsigned short* tp = trunkB + ((size_t)(b * TTIME) + seg * 64) * FMC + c0;
    #pragma unroll 2
    for (int tt = 0; tt < 64; ++tt) {
        const u16x8 tv = *(const u16x8*)(tp + (size_t)tt * FMC);
        float tf[8];
        #pragma unroll
        for (int j = 0; j < 8; ++j) tf[j] = b2f((unsigned short)tv[j]);
        #pragma unroll
        for (int l = 0; l < NTOK; ++l) {
            const float a = __expf(ap[(size_t)l * TTIME + tt] - m_[l]);
            sum_[l] += a;
            #pragma unroll
            for (int j = 0; j < 8; ++j) acc[l][j] += a * tf[j];
        }
    }
    unsigned short* gp = gpart + ((((size_t)(b * NSEG) + seg) * NHEAD + h) * NTOK) * FMC + c0;
    #pragma unroll
    for (int l = 0; l < NTOK; ++l) {
        u16x8 o;
        #pragma unroll
        for (int j = 0; j < 8; ++j) o[j] = (short)f2b(acc[l][j]);
        *(u16x8*)&gp[(size_t)l * FMC] = o;
    }
    if (lane == 0) {
        float2* st = segstats + (((size_t)(b * NSEG) + seg) * NHEAD + h) * NTOK;
        #pragma unroll
        for (int l = 0; l < NTOK; ++l) { float2 s; s.x = m_[l]; s.y = sum_[l]; st[l] = s; }
    }
}

// G[b][hl][c] (+)= softmax-normalized combine of bf16 gpart across segments.
__global__ __launch_bounds__(256) void g_reduce(
    const unsigned short* __restrict__ gpart, const float2* __restrict__ segstats,
    float* __restrict__ G, int first)
{
    const int tid = threadIdx.x;
    const int c = blockIdx.x * 256 + tid;
    const int hl = blockIdx.y;
    const int b = blockIdx.z;
    const int h = hl / NTOK, l = hl % NTOK;
    __shared__ float2 st[NSEG];
    if (tid < NSEG)
        st[tid] = segstats[(((size_t)(b * NSEG) + tid) * NHEAD + h) * NTOK + l];
    __syncthreads();
    float m = -1e30f;
    #pragma unroll 8
    for (int s = 0; s < NSEG; ++s) m = fmaxf(m, st[s].x);
    float denom = 0.f;
    #pragma unroll 8
    for (int s = 0; s < NSEG; ++s) denom += __expf(st[s].x - m) * st[s].y;
    const float invd = 1.0f / denom;
    const unsigned short* p = gpart + (((size_t)(b * NSEG) * NHEAD + h) * NTOK + l) * FMC + c;
    const size_t stride = (size_t)NHEAD * NTOK * FMC;
    float acc = 0.f;
    #pragma unroll 4
    for (int s = 0; s < NSEG; ++s) acc += __expf(st[s].x - m) * b2f(p[s * stride]);
    const float r = acc * invd;
    const size_t id = ((size_t)(b * NHEAD * NTOK) + hl) * FMC + c;
    G[id] = first ? r : (G[id] + r);
}

// dilated 3-tap attention, channel-last bf16; H may alias Q
__global__ __launch_bounds__(256) void dal_elem_cl(
    const unsigned short* __restrict__ Q, const unsigned short* __restrict__ K,
    const unsigned short* __restrict__ V, const float* __restrict__ rel,
    unsigned short* __restrict__ H, int dil)
{
    __shared__ float rels[FMC * 3];
    for (int i = threadIdx.x; i < FMC * 3; i += 256) rels[i] = rel[i];
    __syncthreads();
    const int g = blockIdx.x * 256 + threadIdx.x;
    const int c8 = g & 63;
    const int t = (g >> 6) & (TTIME - 1);
    const int b = g >> 18;
    const size_t base = ((size_t)(b * TTIME + t)) * FMC + c8 * 8;
    const u16x8 q8 = *(const u16x8*)(Q + base);
    const u16x8 k1 = *(const u16x8*)(K + base);
    const u16x8 v1 = *(const u16x8*)(V + base);
    u16x8 k0 = {0,0,0,0,0,0,0,0}, v0 = k0, k2 = k0, v2 = k0;
    const bool in0 = (t - dil) >= 0, in2 = (t + dil) < TTIME;
    if (in0) { k0 = *(const u16x8*)(K + base - (size_t)dil * FMC); v0 = *(const u16x8*)(V + base - (size_t)dil * FMC); }
    if (in2) { k2 = *(const u16x8*)(K + base + (size_t)dil * FMC); v2 = *(const u16x8*)(V + base + (size_t)dil * FMC); }
    u16x8 out;
    #pragma unroll
    for (int j = 0; j < 8; ++j) {
        const int c = c8 * 8 + j;
        const float q = b2f((unsigned short)q8[j]);
        const float kk0 = b2f((unsigned short)k0[j]);
        const float kk1 = b2f((unsigned short)k1[j]);
        const float kk2 = b2f((unsigned short)k2[j]);
        const float vv0 = b2f((unsigned short)v0[j]) + rels[c * 3 + 0];
        const float vv1 = b2f((unsigned short)v1[j]) + rels[c * 3 + 1];
        const float vv2 = b2f((unsigned short)v2[j]) + rels[c * 3 + 2];
        const float s0 = q * kk0, s1 = q * kk1, s2 = q * kk2;
        const float m = fmaxf(s0, fmaxf(s1, s2));
        const float e0 = __expf(s0 - m), e1 = __expf(s1 - m), e2 = __expf(s2 - m);
        const float hres = (e0 * vv0 + e1 * vv1 + e2 * vv2) / (e0 + e1 + e2);
        out[j] = (short)f2b(fmaxf(hres, 0.f));
    }
    *(u16x8*)(H + base) = out;
}

// ---------------------------------------------------------------------------
// final cross attention v2 — coalesced (round-10 verified)
__global__ __launch_bounds__(256) void ca_fused_v2(
    const unsigned short* __restrict__ Qc, const float* __restrict__ kvh,
    unsigned short* __restrict__ o_c)
{
    const int b = blockIdx.y, t0 = blockIdx.x * 64;
    __shared__ float kh_s[NTOK][512];
    __shared__ __align__(16) unsigned short vh_s[NTOK][512];
    __shared__ float s_lds[64][NHEAD * NTOK];
    for (int i = threadIdx.x; i < NTOK * 512; i += 256) {
        const int l = i >> 9, c = i & 511;
        kh_s[l][c] = kvh[((size_t)(b * NTOK) + l) * 1024 + c];
        vh_s[l][c] = f2b(kvh[((size_t)(b * NTOK) + l) * 1024 + 512 + c]);
    }
    __syncthreads();
    {
        const int h = threadIdx.x & 3, tt = threadIdx.x >> 2;
        const unsigned short* qp = Qc + ((size_t)(b * TTIME) + t0 + tt) * FMC + h * 128;
        float s[NTOK];
        #pragma unroll
        for (int l = 0; l < NTOK; ++l) s[l] = 0.f;
        #pragma unroll
        for (int d0 = 0; d0 < 128; d0 += 8) {
            const u16x8 qv = *(const u16x8*)(qp + d0);
            float qf[8];
            #pragma unroll
            for (int j = 0; j < 8; ++j) qf[j] = b2f((unsigned short)qv[j]);
            #pragma unroll
            for (int l = 0; l < NTOK; ++l) {
                float a = 0.f;
                #pragma unroll
                for (int j = 0; j < 8; ++j) a += qf[j] * kh_s[l][h * 128 + d0 + j];
                s[l] += a;
            }
        }
        float mx = -1e30f;
        #pragma unroll
        for (int l = 0; l < NTOK; ++l) { s[l] *= 0.08838834764831845f; mx = fmaxf(mx, s[l]); }
        float sum = 0.f;
        #pragma unroll
        for (int l = 0; l < NTOK; ++l) { s[l] = __expf(s[l] - mx); sum += s[l]; }
        const float inv = 1.0f / sum;
        #pragma unroll
        for (int l = 0; l < NTOK; ++l) s_lds[tt][h * NTOK + l] = s[l] * inv;
    }
    __syncthreads();
    const int lane = threadIdx.x & 63, w = threadIdx.x >> 6;
    const int hh = lane >> 4;
    #pragma unroll
    for (int it = 0; it < 16; ++it) {
        const int tl = it * 4 + w;
        float sv[NTOK];
        #pragma unroll
        for (int l = 0; l < NTOK; ++l) sv[l] = s_lds[tl][hh * NTOK + l];
        float of[8];
        #pragma unroll
        for (int j = 0; j < 8; ++j) of[j] = 0.f;
        #pragma unroll
        for (int l = 0; l < NTOK; ++l) {
            const u16x8 vv = *(const u16x8*)&vh_s[l][lane * 8];
            #pragma unroll
            for (int j = 0; j < 8; ++j) of[j] += sv[l] * b2f((unsigned short)vv[j]);
        }
        u16x8 o8;
        #pragma unroll
        for (int j = 0; j < 8; ++j) o8[j] = (short)f2b(of[j]);
        *(u16x8*)(o_c + ((size_t)(b * TTIME) + t0 + tl) * FMC + lane * 8) = o8;
    }
}

// ---------------------------------------------------------------------------
extern "C" void kernel_launch(void* const* d_in, const int* in_sizes, int n_in,
                              void* d_out, int out_size, void* d_ws, size_t ws_size,
                              hipStream_t stream)
{
    const float* x        = (const float*)d_in[0];
    const float* mask     = (const float*)d_in[1];
    const float* cw1      = (const float*)d_in[2];
    const float* cb1      = (const float*)d_in[3];
    const float* dal_q    = (const float*)d_in[4];
    const float* dal_k    = (const float*)d_in[5];
    const float* dal_v    = (const float*)d_in[6];
    const float* rel_t    = (const float*)d_in[7];
    const float* blk_w    = (const float*)d_in[8];
    const float* blk_b    = (const float*)d_in[9];
    const float* cow      = (const float*)d_in[10];
    const float* cob      = (const float*)d_in[11];
    const float* tokens   = (const float*)d_in[12];
    const float* sm_in_w  = (const float*)d_in[13];
    const float* sm_in_b  = (const float*)d_in[14];
    const float* sm_out_w = (const float*)d_in[15];
    const float* sm_out_b = (const float*)d_in[16];
    const float* ca_in_w  = (const float*)d_in[17];
    const float* ca_out_w = (const float*)d_in[18];
    (void)in_sizes; (void)n_in; (void)out_size; (void)ws_size;

    const size_t BIG = (size_t)BBATCH * FMC * TTIME;   // 16.7M elems
    char* ws = (char*)d_ws;
    size_t off = 0;
    auto alloc = [&](size_t nbytes) {
        void* p = (void*)(ws + off);
        off = (off + nbytes + 255) & ~(size_t)255;
        return p;
    };
    unsigned short* trunkB  = (unsigned short*)alloc(BIG * 2);   // bf16 trunk (only copy)
    unsigned short* bufQ    = (unsigned short*)alloc(BIG * 2);   // q -> h ; (xT low)
    unsigned short* bufK    = (unsigned short*)alloc(BIG * 2);   // k ; Qc  ; (xT high)
    unsigned short* bufV    = (unsigned short*)alloc(BIG * 2);   // v ; o_c
    float* scores  = (float*)alloc((size_t)BBATCH * NHEAD * NTOK * TTIME * 4);
    unsigned short* gpart = (unsigned short*)alloc((size_t)BBATCH * NSEG * NHEAD * NTOK * FMC * 2);
    float2* sstats = (float2*)alloc((size_t)BBATCH * NSEG * NHEAD * NTOK * 8);
    float* G       = (float*)alloc((size_t)BBATCH * NHEAD * NTOK * FMC * 4);
    float* qtok    = (float*)alloc((size_t)NTOK * FMC * 4);
    float* Osum    = (float*)alloc((size_t)BBATCH * NTOK * FMC * 4);
    float* summ5   = (float*)alloc((size_t)BBATCH * NTOK * FMC * 4);
    float* kvh     = (float*)alloc((size_t)BBATCH * NTOK * 1024 * 4);
    unsigned short* Wc   = (unsigned short*)alloc((size_t)FMC * DIMX * 2);
    unsigned short* Wcat = (unsigned short*)alloc((size_t)NLAYERS * WROWS * FMC * 2);
    unsigned short* Wblk = (unsigned short*)alloc((size_t)NLAYERS * FMC * FMC * 2);
    unsigned short* Wqca = (unsigned short*)alloc((size_t)FMC * FMC * 2);
    unsigned short* Wcao = (unsigned short*)alloc((size_t)FMC * FMC * 2);
    unsigned short* Wcow = (unsigned short*)alloc((size_t)NCC * FMC * 2);
    unsigned short* qkh  = (unsigned short*)alloc((size_t)NHEAD * NTOK * FMC * 2);
    unsigned short* xT = bufQ;  // spans bufQ+bufK (contiguous), dead after conv

    const Outs3 no3 = {};

    // --- weight conversion / precompute ---
    {
        const int n0 = FMC * DIMX, n1 = FMC * FMC, n2 = FMC * FMC,
                  n3 = NCC * FMC, n4 = NLAYERS * FMC * FMC;
        const int total = n0 + n1 + n2 + n3 + n4;
        hipLaunchKernelGGL(to_bf16_multi, dim3((total + 255) / 256), dim3(256), 0, stream,
                           cw1, Wc, n0, ca_in_w, Wqca, n1, ca_out_w, Wcao, n2,
                           cow, Wcow, n3, blk_w, Wblk, n4);
    }
    // qtok = tokens @ wq^T + bq   (rows = 10)
    hipLaunchKernelGGL(fast_proj, dim3(FMC / 4, NTOK), dim3(256), 0, stream,
                       tokens, sm_in_w, sm_in_b, qtok, FMC, 1.0f, 1.0f);
    hipLaunchKernelGGL(qkh_build, dim3(NHEAD * NTOK), dim3(256), 0, stream, qtok, sm_in_w, qkh);
    hipLaunchKernelGGL(build_wcat, dim3(2048), dim3(256), 0, stream, dal_q, dal_k, dal_v, qkh, Wcat);

    // --- input transpose + conv ---
    hipLaunchKernelGGL(transpose_x, dim3(TTIME / 64, DIMX / 64, BBATCH), dim3(256), 0, stream, x, xT);
    hipLaunchKernelGGL((gemm_mfma<16,1,0,0,0,0,0>), dim3(TTIME / 128, FMC / 128, BBATCH), dim3(256), 0, stream,
                       Wc, xT, FMC, cb1, nullptr, nullptr, trunkB, nullptr, no3);

    for (int i = 0; i < NLAYERS; ++i) {
        const int dil = 1 << i;
        // fused projections + summary scores: {q,k,v,scores} = Wcat[i] @ trunk (PIPE=1)
        Outs3 o3; o3.p[0] = bufQ; o3.p[1] = bufK; o3.p[2] = bufV;
        hipLaunchKernelGGL((gemm_mfma<8,0,0,0,2,0,1>), dim3(TTIME / 128, WROWS / 128, BBATCH), dim3(256), 0, stream,
                           Wcat + (size_t)i * WROWS * FMC, trunkB, 3 * FMC + NHEAD * NTOK,
                           nullptr, nullptr, nullptr, nullptr, scores, o3);
        // summary path: online-softmax partial accumulation, combine + layer-accumulate
        hipLaunchKernelGGL(g_accum_part, dim3(NSEG, BBATCH), dim3(256), 0, stream,
                           scores, trunkB, gpart, sstats);
        hipLaunchKernelGGL(g_reduce, dim3(FMC / 256, NHEAD * NTOK, BBATCH), dim3(256), 0, stream,
                           gpart, sstats, G, (i == 0) ? 1 : 0);
        // dilated attention (h aliases q in bufQ)
        hipLaunchKernelGGL(dal_elem_cl, dim3((unsigned)(BIG / 256 / 8)), dim3(256), 0, stream,
                           bufQ, bufK, bufV, rel_t + (size_t)i * FMC * 3, bufQ, dil);
        // trunk = (trunk + blk_w @ h + blk_b) * mask   (in-place bf16 resid)
        hipLaunchKernelGGL((gemm_mfma<8,1,1,1,0,0,0>), dim3(TTIME / 128, FMC / 128, BBATCH), dim3(256), 0, stream,
                           Wblk + (size_t)i * FMC * FMC, bufQ, FMC,
                           blk_b + (size_t)i * FMC, trunkB, mask, trunkB, nullptr, no3);
    }

    // --- deferred summary (linear): O = Wv@G + 5bv ; summ5 = sm_out(O)/5 ; kvh ---
    hipLaunchKernelGGL(fast_sm_ov, dim3(FMC / 4, BBATCH * NTOK), dim3(256), 0, stream,
                       G, sm_in_w, sm_in_b, Osum);
    hipLaunchKernelGGL(fast_proj, dim3(FMC / 4, BBATCH * NTOK), dim3(256), 0, stream,
                       Osum, sm_out_w, sm_out_b, summ5, FMC, 0.2f, 1.0f);
    hipLaunchKernelGGL(fast_proj, dim3(1024 / 4, BBATCH * NTOK), dim3(256), 0, stream,
                       summ5, ca_in_w + (size_t)FMC * FMC, nullptr, kvh, 1024, 1.0f, 0.0f);

    // --- final cross attention ---
    hipLaunchKernelGGL((gemm_mfma<8,0,0,0,0,0,1>), dim3(TTIME / 128, FMC / 128, BBATCH), dim3(256), 0, stream,
                       Wqca, trunkB, FMC, nullptr, nullptr, nullptr, bufK, nullptr, no3);
    hipLaunchKernelGGL(ca_fused_v2, dim3(TTIME / 64, BBATCH), dim3(256), 0, stream,
                       bufK, kvh, bufV);
    // trunk += ca_out_w @ o_c   (in-place bf16 resid)
    hipLaunchKernelGGL((gemm_mfma<8,0,1,0,0,0,0>), dim3(TTIME / 128, FMC / 128, BBATCH), dim3(256), 0, stream,
                       Wcao, bufV, FMC, nullptr, trunkB, nullptr, trunkB, nullptr, no3);
    // d_out = (cow @ trunk + cob) * mask   (channel-major fp32)
    hipLaunchKernelGGL((gemm_mfma<8,1,0,1,0,1,0>), dim3(TTIME / 128, 2, BBATCH), dim3(256), 0, stream,
                       Wcow, trunkB, NCC, cob, nullptr, mask, nullptr, (float*)d_out, no3);
}